// Round 1
// baseline (739.914 us; speedup 1.0000x reference)
//
#include <hip/hip_runtime.h>
#include <hip/hip_fp16.h>

#define BSZ 256
#define CCH 512
#define HW_ 81
#define DD 9
#define CH 41472   /* CCH*HW_ */

/* ws layout (floats) */
#define WS_W1T   0        /* [162][81] folded+transposed se_att_w1 (legacy, unused) */
#define WS_TSE   13122    /* [81]  folded se_att bias */
#define WS_S2    13203    /* [512] sa_key bn scale */
#define WS_T2    13715    /* [512] sa_key bn bias */
#define WS_W1S   14227    /* [512][16] folded sa_att_w1 */
#define WS_T1    22419    /* [512] folded sa_att bias */
#define WS_A2    22932    /* [256][64][81] SaMCA attention */
#define WS_ATT   1350036  /* [256][9][512] SeMCA attention */
#define WS_W1F   2529684  /* [96][192] fp16 folded se_att_w1, zero-padded (ushorts) */
#define WS_TOTALP 22931   /* params region end */
#define PREP_N   41363    /* 22931 + 96*192/2 */

typedef _Float16 half8 __attribute__((ext_vector_type(8)));
typedef float f32x4 __attribute__((ext_vector_type(4)));

__device__ __forceinline__ float h2f(unsigned short u) {
    return __half2float(__ushort_as_half(u));
}
__device__ __forceinline__ unsigned short f2h(float f) {
    return __half_as_ushort(__float2half(f));
}

__global__ void prep_kernel(const float* __restrict__ se_att_w1,  // 81*162
                            const float* __restrict__ se_att_bn,  // 4*81
                            const float* __restrict__ sa_key_bn,  // 4*512
                            const float* __restrict__ sa_att_w1,  // 512*16
                            const float* __restrict__ sa_att_bn,  // 4*512
                            float* __restrict__ ws) {
    int idx = blockIdx.x * blockDim.x + threadIdx.x;
    if (idx < 13122) {
        int r = idx / 81, o = idx % 81;
        float g = se_att_bn[o], v = se_att_bn[243 + o];
        float s = g * rsqrtf(v + 1e-5f);
        ws[WS_W1T + idx] = se_att_w1[o * 162 + r] * s;
    } else if (idx < 13203) {
        int o = idx - 13122;
        float g = se_att_bn[o], b = se_att_bn[81 + o], m = se_att_bn[162 + o], v = se_att_bn[243 + o];
        float s = g * rsqrtf(v + 1e-5f);
        ws[WS_TSE + o] = b - m * s;
    } else if (idx < 13715) {
        int c = idx - 13203;
        float g = sa_key_bn[c], v = sa_key_bn[1536 + c];
        ws[WS_S2 + c] = g * rsqrtf(v + 1e-5f);
    } else if (idx < 14227) {
        int c = idx - 13715;
        float g = sa_key_bn[c], b = sa_key_bn[512 + c], m = sa_key_bn[1024 + c], v = sa_key_bn[1536 + c];
        float s = g * rsqrtf(v + 1e-5f);
        ws[WS_T2 + c] = b - m * s;
    } else if (idx < 22419) {
        int e = idx - 14227;
        int o = e >> 4;
        float g = sa_att_bn[o], v = sa_att_bn[1536 + o];
        float s = g * rsqrtf(v + 1e-5f);
        ws[WS_W1S + e] = sa_att_w1[e] * s;
    } else if (idx < WS_TOTALP) {
        int o = idx - 22419;
        float g = sa_att_bn[o], b = sa_att_bn[512 + o], m = sa_att_bn[1024 + o], v = sa_att_bn[1536 + o];
        float s = g * rsqrtf(v + 1e-5f);
        ws[WS_T1 + o] = b - m * s;
    } else if (idx < PREP_N) {
        // fp16 folded W1, padded [96][192] (two ushorts per float slot)
        int e2 = (idx - WS_TOTALP) * 2;
        unsigned int packed = 0;
        #pragma unroll
        for (int q = 0; q < 2; ++q) {
            int e = e2 + q;
            int row = e / 192, k = e - row * 192;
            unsigned short val = 0;
            if (row < 81 && k < 162) {
                float g = se_att_bn[row], v = se_att_bn[243 + row];
                float s = g * rsqrtf(v + 1e-5f);
                val = f2h(se_att_w1[row * 162 + k] * s);
            }
            packed |= ((unsigned int)val) << (16 * q);
        }
        ((unsigned int*)(ws + WS_W1F))[idx - WS_TOTALP] = packed;
    }
}

// ======== Kernel SA: SaMCA attention, grid = (batch, ch-half), 256 thr =====
// LDS ~66.7 KB -> 2 blocks/CU (8 waves). No MFMA, no large arrays -> no spill.
__global__ __launch_bounds__(256) void sa_kernel(
    const float* __restrict__ x,
    const float* __restrict__ sa_key_w,   // 512*9
    const float* __restrict__ sa_att_w2,  // 64*8
    const float* __restrict__ sa_att_b2,  // 64
    float* __restrict__ ws)
{
    __shared__ __align__(16) unsigned short xbh[256 * HW_]; // 41472 B, this half's ch
    __shared__ unsigned short wkbL[256 * DD];               //  4608 B
    __shared__ float s2L[256];
    __shared__ float t2L[256];
    __shared__ float w1sL[256 * 16];                        // 16384 B
    __shared__ float saw2L[256];
    __shared__ float b2L[32];
    __shared__ float t1L[256];

    const int bid = blockIdx.x;
    const int b = bid >> 1;
    const int h = bid & 1;
    const int c0 = h * 256;
    const int t = threadIdx.x;

    // ---- stage ----
    {
        const float4* x4 = (const float4*)(x + (size_t)b * CH + (size_t)c0 * 81);
        for (int v = t; v < 5184; v += 256) {
            float4 q = x4[v];
            ushort4 s4;
            s4.x = f2h(q.x); s4.y = f2h(q.y); s4.z = f2h(q.z); s4.w = f2h(q.w);
            *(ushort4*)(&xbh[4 * v]) = s4;
        }
        for (int v = t; v < 256 * DD; v += 256) wkbL[v] = f2h(sa_key_w[c0 * 9 + v]);
        s2L[t] = ws[WS_S2 + c0 + t];
        t2L[t] = ws[WS_T2 + c0 + t];
        for (int v = t; v < 256 * 16; v += 256) w1sL[v] = ws[WS_W1S + c0 * 16 + v];
        saw2L[t] = sa_att_w2[c0 + t];
        if (t < 32) b2L[t] = sa_att_b2[h * 32 + t];
        t1L[t] = ws[WS_T1 + c0 + t];
    }
    __syncthreads();

    // ---- SaMCA attention for groups [h*32, h*32+32) -> ws A2 ----
    {
        const int gl = t >> 3, sub = t & 7;     // local group 0..31, 8 lanes each
        const int g = h * 32 + gl;
        const float b2g = b2L[gl];
        float a2v[11];
        #pragma unroll
        for (int k = 0; k < 11; ++k) {
            int p = sub + 8 * k;
            float res = -1e30f;
            if (p < 81) {
                int y = p / 9, xx = p - (p / 9) * 9;
                float z[8];
                #pragma unroll
                for (int o = 0; o < 8; ++o) z[o] = t1L[8 * gl + o];
                #pragma unroll
                for (int j = 0; j < 8; ++j) {
                    int cl = 8 * gl + j;        // local channel
                    float conv = 0.f;
                    #pragma unroll
                    for (int ky = 0; ky < 3; ++ky) {
                        int yy = y + ky - 1;
                        if (yy < 0 || yy > 8) continue;
                        #pragma unroll
                        for (int kx = 0; kx < 3; ++kx) {
                            int xc = xx + kx - 1;
                            if (xc < 0 || xc > 8) continue;
                            conv = fmaf(h2f(xbh[cl * 81 + yy * 9 + xc]),
                                        h2f(wkbL[cl * 9 + ky * 3 + kx]), conv);
                        }
                    }
                    float kv = fmaxf(conv * s2L[cl] + t2L[cl], 0.f);
                    float xv = h2f(xbh[cl * 81 + p]);
                    #pragma unroll
                    for (int o = 0; o < 8; ++o) {
                        const float* w1o = &w1sL[(8 * gl + o) * 16];
                        z[o] = fmaf(w1o[2 * j], kv, z[o]);
                        z[o] = fmaf(w1o[2 * j + 1], xv, z[o]);
                    }
                }
                float s = b2g;
                #pragma unroll
                for (int o = 0; o < 8; ++o)
                    s = fmaf(saw2L[gl * 8 + o], fmaxf(z[o], 0.f), s);
                res = s;
            }
            a2v[k] = res;
        }
        float m = a2v[0];
        #pragma unroll
        for (int k = 1; k < 11; ++k) m = fmaxf(m, a2v[k]);
        #pragma unroll
        for (int off = 1; off < 8; off <<= 1) m = fmaxf(m, __shfl_xor(m, off, 64));
        float ls = 0.f;
        float ev[11];
        #pragma unroll
        for (int k = 0; k < 11; ++k) { ev[k] = __expf(a2v[k] - m); ls += ev[k]; }
        #pragma unroll
        for (int off = 1; off < 8; off <<= 1) ls += __shfl_xor(ls, off, 64);
        float inv = 1.f / ls;
        float* a2out = ws + WS_A2 + (size_t)b * 5184;
        #pragma unroll
        for (int k = 0; k < 11; ++k) {
            int p = sub + 8 * k;
            if (p < 81) a2out[g * 81 + p] = ev[k] * inv;
        }
    }
}

// ======== Kernel SE: SeMCA attention via MFMA, grid = (batch x 4 quarters) ==
// Block handles cols [q*128, q*128+128). KQ^T tile built once in LDS (no
// per-pass rebuild barriers); acc[6][2] = 48 regs/lane; epilogue fully
// unrolled (static acc indices -> registers, no scratch).
// LDS ~58 KB -> 2 blocks/CU. blockIdx mapping: b = idx&255 so all 4 quarters
// of a batch land on the same XCD (round-robin %8 => xcd = b%8).
__global__ __launch_bounds__(256) void se_kernel(
    const float* __restrict__ x,
    const float* __restrict__ se_key_w,   // 81*9
    const float* __restrict__ se_key_b,   // 81
    const float* __restrict__ se_att_w2,  // 9*81
    const float* __restrict__ se_att_b2,  // 9
    float* __restrict__ ws)
{
    __shared__ __align__(16) unsigned short kqs[128 * 200];  // 51200 B [col][k]
    __shared__ float wseL[DD * HW_];                         //  2916 B wse[tau][p]
    __shared__ float bseL[HW_];
    __shared__ float w2L[DD * 96];                           //  3456 B
    __shared__ float tseL[96];

    const int pb = blockIdx.x;
    const int b = pb & 255;
    const int q = pb >> 8;
    const int c0 = q * 128;
    const int t = threadIdx.x;
    const float* xb = x + (size_t)b * CH;

    // ---- stage small weights ----
    for (int v = t; v < DD * HW_; v += 256) {
        int tau = v / 81, p = v - 81 * tau;
        wseL[tau * 81 + p] = se_key_w[p * 9 + tau];
    }
    if (t < HW_) bseL[t] = se_key_b[t];
    for (int v = t; v < DD * 96; v += 256) {
        int d = v / 96, row = v - 96 * d;
        w2L[v] = (row < 81) ? se_att_w2[d * 81 + row] : 0.f;
    }
    if (t < 96) tseL[t] = (t < 81) ? ws[WS_TSE + t] : 0.f;
    __syncthreads();

    // ---- build KQ^T tile: kqs[jl][k] for k in [0,200) ----
    // q-rows (k < 81): KQ[k][j] = x.flat[k*512 + j]   (coalesced reads)
    for (int v = t; v < 128 * 81; v += 256) {
        int k = v >> 7, jl = v & 127;
        kqs[jl * 200 + k] = f2h(xb[k * 512 + c0 + jl]);
    }
    // k-rows (81 <= k < 162): spectral depthwise conv along flat axis
    for (int v = t; v < 128 * 81; v += 256) {
        int kk = v >> 7, jl = v & 127;
        int e = kk * 512 + c0 + jl;
        int p = e % 81;
        float s = bseL[p];
        #pragma unroll
        for (int tau = 0; tau < 9; ++tau) {
            int flat = e + (tau - 4) * 81;
            if (flat >= 0 && flat < CH)
                s = fmaf(xb[flat], wseL[tau * 81 + p], s);
        }
        kqs[jl * 200 + 81 + kk] = f2h(s);
    }
    // zero pad rows 162..199 (W1f cols there are zero too; keep clean anyway)
    for (int v = t; v < 128 * 38; v += 256) {
        int k = v >> 7, jl = v & 127;
        kqs[jl * 200 + 162 + k] = 0;
    }
    __syncthreads();

    // ---- MFMA K-loop: C[96 x 128] = W1f[96 x 192] * KQ[192 x 128-slice] ----
    const int wv = t >> 6;          // wave 0..3, owns cols [c0+wv*32, +32)
    const int lane = t & 63;
    const int quad = lane >> 4;
    const int l15 = lane & 15;
    const unsigned short* w1f = (const unsigned short*)(ws + WS_W1F);

    f32x4 acc[6][2];
    #pragma unroll
    for (int m = 0; m < 6; ++m)
        #pragma unroll
        for (int n = 0; n < 2; ++n)
            acc[m][n] = (f32x4){0.f, 0.f, 0.f, 0.f};

    #pragma unroll 1
    for (int pass = 0; pass < 6; ++pass) {
        half8 bfr[2];
        #pragma unroll
        for (int n = 0; n < 2; ++n)
            bfr[n] = *(const half8*)&kqs[(wv * 32 + n * 16 + l15) * 200 + pass * 32 + quad * 8];
        #pragma unroll
        for (int m = 0; m < 6; ++m) {
            half8 afr = *(const half8*)&w1f[(m * 16 + l15) * 192 + pass * 32 + quad * 8];
            #pragma unroll
            for (int n = 0; n < 2; ++n)
                acc[m][n] = __builtin_amdgcn_mfma_f32_16x16x32_f16(afr, bfr[n], acc[m][n], 0, 0, 0);
        }
    }

    // ---- epilogue: relu(C + tse) -> fold 9x81 -> softmax -> ws ATT ----
    // Fully unrolled n-loop: every acc index is compile-time (rule #20).
    float* attout = ws + WS_ATT + (size_t)b * 4608;
    #pragma unroll
    for (int n = 0; n < 2; ++n) {
        float pd[9];
        #pragma unroll
        for (int d = 0; d < 9; ++d) pd[d] = 0.f;
        #pragma unroll
        for (int m = 0; m < 6; ++m) {
            #pragma unroll
            for (int reg = 0; reg < 4; ++reg) {
                int row = m * 16 + quad * 4 + reg;
                float z = fmaxf(acc[m][n][reg] + tseL[row], 0.f);
                #pragma unroll
                for (int d = 0; d < 9; ++d)
                    pd[d] = fmaf(w2L[d * 96 + row], z, pd[d]);
            }
        }
        #pragma unroll
        for (int d = 0; d < 9; ++d) {
            pd[d] += __shfl_xor(pd[d], 16, 64);
            pd[d] += __shfl_xor(pd[d], 32, 64);
        }
        if (quad == 0) {
            int j = c0 + wv * 32 + n * 16 + l15;
            float ad[9];
            #pragma unroll
            for (int d = 0; d < 9; ++d) ad[d] = pd[d] + se_att_b2[d];
            float mm = ad[0];
            #pragma unroll
            for (int d = 1; d < 9; ++d) mm = fmaxf(mm, ad[d]);
            float ls = 0.f;
            #pragma unroll
            for (int d = 0; d < 9; ++d) { ad[d] = __expf(ad[d] - mm); ls += ad[d]; }
            float inv = 1.f / ls;
            #pragma unroll
            for (int d = 0; d < 9; ++d) attout[d * 512 + j] = ad[d] * inv;
        }
    }
}

// ============== Kernel B: combine, block = (batch, 64-channel tile) =========
__global__ __launch_bounds__(256) void combine_kernel(
    const float* __restrict__ x,
    const float* __restrict__ alpha,
    const float* __restrict__ sa_key_w,   // 512*9
    const float* __restrict__ se_key_w,   // 81*9
    const float* __restrict__ se_key_b,   // 81
    const float* __restrict__ se_val_w,   // 512*9
    const float* __restrict__ se_val_b,   // 512
    const float* __restrict__ ws,
    float* __restrict__ out)
{
    __shared__ float xs[72 * 81];   // channels c0-4 .. c0+67 (zero-pad OOB)
    __shared__ float vs[72 * 81];   // depthwise-v plane (zero OOB, matches pad_v)
    __shared__ float wvL[72 * 9];
    __shared__ float bvL[72];
    __shared__ float wkL[64 * 9];
    __shared__ float s2L[64];
    __shared__ float t2L[64];
    __shared__ float wseL[81 * 9];
    __shared__ float bseL[81];
    __shared__ float attL[9 * 64];
    __shared__ float a2L[8 * 81];
    /* ~60.5 KB */

    const int bid = blockIdx.x;
    const int b = bid >> 3;
    const int tile = bid & 7;
    const int c0 = tile * 64;
    const int t = threadIdx.x;
    const int f0 = (c0 - 4) * 81;

    for (int idx = t; idx < 5832; idx += 256) {
        int g = f0 + idx;
        xs[idx] = (g >= 0 && g < CH) ? x[(size_t)b * CH + g] : 0.f;
    }
    for (int idx = t; idx < 648; idx += 256) {
        int cc = c0 - 4 + idx / 9;
        wvL[idx] = (cc >= 0 && cc < 512) ? se_val_w[cc * 9 + idx % 9] : 0.f;
    }
    if (t < 72) {
        int cc = c0 - 4 + t;
        bvL[t] = (cc >= 0 && cc < 512) ? se_val_b[cc] : 0.f;
    }
    for (int idx = t; idx < 576; idx += 256) wkL[idx] = sa_key_w[c0 * 9 + idx];
    if (t < 64) { s2L[t] = ws[WS_S2 + c0 + t]; t2L[t] = ws[WS_T2 + c0 + t]; }
    for (int idx = t; idx < 729; idx += 256) wseL[idx] = se_key_w[idx];
    if (t < 81) bseL[t] = se_key_b[t];
    for (int idx = t; idx < 576; idx += 256)
        attL[idx] = ws[WS_ATT + (size_t)b * 4608 + (idx >> 6) * 512 + c0 + (idx & 63)];
    for (int idx = t; idx < 648; idx += 256)
        a2L[idx] = ws[WS_A2 + (size_t)b * 5184 + tile * 648 + idx];
    __syncthreads();

    // depthwise-v plane (3x3 conv + bias), zero for OOB channels (= pad_v)
    for (int idx = t; idx < 5832; idx += 256) {
        int i = idx / 81, p = idx - 81 * i;
        int cc = c0 - 4 + i;
        float r = 0.f;
        if (cc >= 0 && cc < 512) {
            int y = p / 9, xx = p - 9 * (p / 9);
            float s = 0.f;
            #pragma unroll
            for (int ky = 0; ky < 3; ++ky) {
                int yy = y + ky - 1;
                if (yy < 0 || yy > 8) continue;
                #pragma unroll
                for (int kx = 0; kx < 3; ++kx) {
                    int xc = xx + kx - 1;
                    if (xc < 0 || xc > 8) continue;
                    s = fmaf(xs[i * 81 + yy * 9 + xc], wvL[i * 9 + ky * 3 + kx], s);
                }
            }
            r = s + bvL[i];
        }
        vs[idx] = r;
    }
    __syncthreads();

    const float av = alpha[0];
    float* outb = out + (size_t)b * CH + (size_t)c0 * 81;
    #pragma unroll 1
    for (int e = t; e < 5184; e += 256) {
        int cl = e / 81, p = e - 81 * cl;
        int y = p / 9, xx = p - 9 * y;
        // spatial key (3x3 dw conv -> bn -> relu)
        float sk = 0.f;
        #pragma unroll
        for (int ky = 0; ky < 3; ++ky) {
            int yy = y + ky - 1;
            if (yy < 0 || yy > 8) continue;
            #pragma unroll
            for (int kx = 0; kx < 3; ++kx) {
                int xc = xx + kx - 1;
                if (xc < 0 || xc > 8) continue;
                sk = fmaf(xs[(cl + 4) * 81 + yy * 9 + xc], wkL[cl * 9 + ky * 3 + kx], sk);
            }
        }
        float k1s = fmaxf(sk * s2L[cl] + t2L[cl], 0.f);
        // spectral attention combine
        float o1 = 0.f;
        #pragma unroll
        for (int d = 0; d < 9; ++d)
            o1 = fmaf(vs[(cl + d) * 81 + p], attL[d * 64 + cl], o1);
        // spectral key value (k1) added to out1
        float k1se = bseL[p];
        #pragma unroll
        for (int tau = 0; tau < 9; ++tau)
            k1se = fmaf(xs[(cl + tau) * 81 + p], wseL[p * 9 + tau], k1se);
        float out2 = k1s + a2L[(cl >> 3) * 81 + p] * xs[(cl + 4) * 81 + p];
        outb[cl * 81 + p] = av * (o1 + k1se) + (1.f - av) * out2;
    }
}

extern "C" void kernel_launch(void* const* d_in, const int* in_sizes, int n_in,
                              void* d_out, int out_size, void* d_ws, size_t ws_size,
                              hipStream_t stream) {
    const float* x          = (const float*)d_in[0];
    const float* alpha      = (const float*)d_in[1];
    const float* sa_key_w   = (const float*)d_in[2];
    const float* sa_key_bn  = (const float*)d_in[3];
    const float* sa_att_w1  = (const float*)d_in[4];
    const float* sa_att_bn  = (const float*)d_in[5];
    const float* sa_att_w2  = (const float*)d_in[6];
    const float* sa_att_b2  = (const float*)d_in[7];
    const float* se_key_w   = (const float*)d_in[8];
    const float* se_key_b   = (const float*)d_in[9];
    const float* se_att_w1  = (const float*)d_in[10];
    const float* se_att_bn  = (const float*)d_in[11];
    const float* se_att_w2  = (const float*)d_in[12];
    const float* se_att_b2  = (const float*)d_in[13];
    const float* se_val_w   = (const float*)d_in[14];
    const float* se_val_b   = (const float*)d_in[15];
    float* ws = (float*)d_ws;
    float* outp = (float*)d_out;

    prep_kernel<<<(PREP_N + 255) / 256, 256, 0, stream>>>(
        se_att_w1, se_att_bn, sa_key_bn, sa_att_w1, sa_att_bn, ws);
    sa_kernel<<<BSZ * 2, 256, 0, stream>>>(
        x, sa_key_w, sa_att_w2, sa_att_b2, ws);
    se_kernel<<<BSZ * 4, 256, 0, stream>>>(
        x, se_key_w, se_key_b, se_att_w2, se_att_b2, ws);
    combine_kernel<<<BSZ * 8, 256, 0, stream>>>(
        x, alpha, sa_key_w, se_key_w, se_key_b, se_val_w, se_val_b, ws, outp);
}

// Round 2
// 538.997 us; speedup vs baseline: 1.3728x; 1.3728x over previous
//
#include <hip/hip_runtime.h>
#include <hip/hip_fp16.h>

#define BSZ 256
#define CCH 512
#define HW_ 81
#define DD 9
#define CH 41472   /* CCH*HW_ */

/* ws layout (floats) */
#define WS_W1T   0        /* [162][81] folded+transposed se_att_w1 (legacy, unused) */
#define WS_TSE   13122    /* [81]  folded se_att bias */
#define WS_S2    13203    /* [512] sa_key bn scale */
#define WS_T2    13715    /* [512] sa_key bn bias */
#define WS_W1S   14227    /* [512][16] folded sa_att_w1 */
#define WS_T1    22419    /* [512] folded sa_att bias */
#define WS_A2    22932    /* [256][64][81] SaMCA attention */
#define WS_ATT   1350036  /* [256][9][512] SeMCA attention */
#define WS_W1F   2529684  /* [96][192] fp16 folded se_att_w1, zero-padded (ushorts) */
#define WS_TOTALP 22931   /* params region end */
#define PREP_N   41363    /* 22931 + 96*192/2 */

typedef _Float16 half8 __attribute__((ext_vector_type(8)));
typedef float f32x4 __attribute__((ext_vector_type(4)));

__device__ __forceinline__ float h2f(unsigned short u) {
    return __half2float(__ushort_as_half(u));
}
__device__ __forceinline__ unsigned short f2h(float f) {
    return __half_as_ushort(__float2half(f));
}

__global__ void prep_kernel(const float* __restrict__ se_att_w1,  // 81*162
                            const float* __restrict__ se_att_bn,  // 4*81
                            const float* __restrict__ sa_key_bn,  // 4*512
                            const float* __restrict__ sa_att_w1,  // 512*16
                            const float* __restrict__ sa_att_bn,  // 4*512
                            float* __restrict__ ws) {
    int idx = blockIdx.x * blockDim.x + threadIdx.x;
    if (idx < 13122) {
        int r = idx / 81, o = idx % 81;
        float g = se_att_bn[o], v = se_att_bn[243 + o];
        float s = g * rsqrtf(v + 1e-5f);
        ws[WS_W1T + idx] = se_att_w1[o * 162 + r] * s;
    } else if (idx < 13203) {
        int o = idx - 13122;
        float g = se_att_bn[o], b = se_att_bn[81 + o], m = se_att_bn[162 + o], v = se_att_bn[243 + o];
        float s = g * rsqrtf(v + 1e-5f);
        ws[WS_TSE + o] = b - m * s;
    } else if (idx < 13715) {
        int c = idx - 13203;
        float g = sa_key_bn[c], v = sa_key_bn[1536 + c];
        ws[WS_S2 + c] = g * rsqrtf(v + 1e-5f);
    } else if (idx < 14227) {
        int c = idx - 13715;
        float g = sa_key_bn[c], b = sa_key_bn[512 + c], m = sa_key_bn[1024 + c], v = sa_key_bn[1536 + c];
        float s = g * rsqrtf(v + 1e-5f);
        ws[WS_T2 + c] = b - m * s;
    } else if (idx < 22419) {
        int e = idx - 14227;
        int o = e >> 4;
        float g = sa_att_bn[o], v = sa_att_bn[1536 + o];
        float s = g * rsqrtf(v + 1e-5f);
        ws[WS_W1S + e] = sa_att_w1[e] * s;
    } else if (idx < WS_TOTALP) {
        int o = idx - 22419;
        float g = sa_att_bn[o], b = sa_att_bn[512 + o], m = sa_att_bn[1024 + o], v = sa_att_bn[1536 + o];
        float s = g * rsqrtf(v + 1e-5f);
        ws[WS_T1 + o] = b - m * s;
    } else if (idx < PREP_N) {
        // fp16 folded W1, padded [96][192] (two ushorts per float slot)
        int e2 = (idx - WS_TOTALP) * 2;
        unsigned int packed = 0;
        #pragma unroll
        for (int q = 0; q < 2; ++q) {
            int e = e2 + q;
            int row = e / 192, k = e - row * 192;
            unsigned short val = 0;
            if (row < 81 && k < 162) {
                float g = se_att_bn[row], v = se_att_bn[243 + row];
                float s = g * rsqrtf(v + 1e-5f);
                val = f2h(se_att_w1[row * 162 + k] * s);
            }
            packed |= ((unsigned int)val) << (16 * q);
        }
        ((unsigned int*)(ws + WS_W1F))[idx - WS_TOTALP] = packed;
    }
}

// ======== Kernel SA: SaMCA attention, grid = (batch x 4 ch-quarters) ========
// Two-pass, low-VGPR rewrite. Round-1 version spilled ~2.1 KB/thread
// (VGPR=256, WRITE_SIZE=282MB for a 5.3MB output) because the 11x8x8
// mega-unrolled loop kept a2v[11]/ev[11]/z[8] + hoisted loads live.
// Now: Pass A computes kv-plane into LDS once; Pass B keeps z[8][6]
// statically indexed with the j-loop NOT unrolled -> ~120 VGPR, no scratch.
// LDS ~75 KB -> 2 blocks/CU.
__global__ __launch_bounds__(256) void sa_kernel(
    const float* __restrict__ x,
    const float* __restrict__ sa_key_w,   // 512*9
    const float* __restrict__ sa_att_w2,  // 64*8
    const float* __restrict__ sa_att_b2,  // 64
    float* __restrict__ ws)
{
    __shared__ __align__(16) unsigned short xbh[128 * HW_]; // 20736 B fp16 x quarter
    __shared__ float kvf[128 * HW_];                        // 41472 B f32 kv plane
    __shared__ unsigned short wkbL[128 * DD];               //  2304 B
    __shared__ float s2L[128];
    __shared__ float t2L[128];
    __shared__ float w1sL[128 * 16];                        //  8192 B
    __shared__ float saw2L[128];
    __shared__ float b2L[16];
    __shared__ float t1L[128];
    /* total ~74.9 KB */

    const int bid = blockIdx.x;
    const int b = bid >> 2;
    const int qr = bid & 3;
    const int c0 = qr * 128;
    const int t = threadIdx.x;

    // ---- stage ----
    {
        const float4* x4 = (const float4*)(x + (size_t)b * CH + (size_t)c0 * 81);
        for (int v = t; v < 128 * 81 / 4; v += 256) {
            float4 q = x4[v];
            ushort4 s4;
            s4.x = f2h(q.x); s4.y = f2h(q.y); s4.z = f2h(q.z); s4.w = f2h(q.w);
            *(ushort4*)(&xbh[4 * v]) = s4;
        }
        for (int v = t; v < 128 * DD; v += 256) wkbL[v] = f2h(sa_key_w[c0 * 9 + v]);
        if (t < 128) {
            s2L[t] = ws[WS_S2 + c0 + t];
            t2L[t] = ws[WS_T2 + c0 + t];
            saw2L[t] = sa_att_w2[c0 + t];
            t1L[t] = ws[WS_T1 + c0 + t];
        }
        for (int v = t; v < 128 * 16; v += 256) w1sL[v] = ws[WS_W1S + c0 * 16 + v];
        if (t < 16) b2L[t] = sa_att_b2[qr * 16 + t];
    }
    __syncthreads();

    // ---- Pass A: kv = relu(bn(dwconv3x3(x))), f32 into LDS ----
    #pragma unroll 2
    for (int idx = t; idx < 128 * 81; idx += 256) {
        int c = idx / 81, p = idx - 81 * c;
        int y = p / 9, xx = p - 9 * y;
        float conv = 0.f;
        #pragma unroll
        for (int ky = 0; ky < 3; ++ky) {
            int yy = y + ky - 1;
            if (yy < 0 || yy > 8) continue;
            #pragma unroll
            for (int kx = 0; kx < 3; ++kx) {
                int xc = xx + kx - 1;
                if (xc < 0 || xc > 8) continue;
                conv = fmaf(h2f(xbh[c * 81 + yy * 9 + xc]),
                            h2f(wkbL[c * 9 + ky * 3 + kx]), conv);
            }
        }
        kvf[idx] = fmaxf(conv * s2L[c] + t2L[c], 0.f);
    }
    __syncthreads();

    // ---- Pass B: attention logits + softmax ----
    // 16 groups x 16 lanes; lane sub handles pixels p = sub + 16k, k<6.
    {
        const int g = t >> 4, sub = t & 15;
        const int cb = g * 8;                    // local channel base
        float z[8][6];
        #pragma unroll
        for (int o = 0; o < 8; ++o)
            #pragma unroll
            for (int k = 0; k < 6; ++k)
                z[o][k] = t1L[cb + o];

        #pragma unroll 1
        for (int j = 0; j < 8; ++j) {
            float wk[8], wx[8];
            #pragma unroll
            for (int o = 0; o < 8; ++o) {
                wk[o] = w1sL[(cb + o) * 16 + 2 * j];
                wx[o] = w1sL[(cb + o) * 16 + 2 * j + 1];
            }
            const int rowb = (cb + j) * 81;
            #pragma unroll
            for (int k = 0; k < 6; ++k) {
                int p = sub + 16 * k;
                if (p > 80) p = 80;              // clamp; masked at softmax
                float kv = kvf[rowb + p];
                float xv = h2f(xbh[rowb + p]);
                #pragma unroll
                for (int o = 0; o < 8; ++o) {
                    z[o][k] = fmaf(wk[o], kv, z[o][k]);
                    z[o][k] = fmaf(wx[o], xv, z[o][k]);
                }
            }
        }

        float a2v[6];
        const float b2g = b2L[g];
        #pragma unroll
        for (int k = 0; k < 6; ++k) {
            float s = b2g;
            #pragma unroll
            for (int o = 0; o < 8; ++o)
                s = fmaf(saw2L[cb + o], fmaxf(z[o][k], 0.f), s);
            int p = sub + 16 * k;
            a2v[k] = (p < 81) ? s : -1e30f;
        }

        // softmax over the 81 pixels (16 lanes x 6 slots, masked)
        float m = a2v[0];
        #pragma unroll
        for (int k = 1; k < 6; ++k) m = fmaxf(m, a2v[k]);
        #pragma unroll
        for (int off = 1; off < 16; off <<= 1) m = fmaxf(m, __shfl_xor(m, off, 64));
        float ls = 0.f;
        float ev[6];
        #pragma unroll
        for (int k = 0; k < 6; ++k) { ev[k] = __expf(a2v[k] - m); ls += ev[k]; }
        #pragma unroll
        for (int off = 1; off < 16; off <<= 1) ls += __shfl_xor(ls, off, 64);
        float inv = 1.f / ls;

        float* a2out = ws + WS_A2 + (size_t)b * 5184 + (size_t)(qr * 16 + g) * 81;
        #pragma unroll
        for (int k = 0; k < 6; ++k) {
            int p = sub + 16 * k;
            if (p < 81) a2out[p] = ev[k] * inv;
        }
    }
}

// ======== Kernel SE: SeMCA attention via MFMA, grid = (batch x 4 quarters) ==
// Block handles cols [q*128, q*128+128). KQ^T tile built once in LDS (no
// per-pass rebuild barriers); acc[6][2] = 48 regs/lane; epilogue fully
// unrolled (static acc indices -> registers, no scratch).
// LDS ~58 KB -> 2 blocks/CU.
__global__ __launch_bounds__(256) void se_kernel(
    const float* __restrict__ x,
    const float* __restrict__ se_key_w,   // 81*9
    const float* __restrict__ se_key_b,   // 81
    const float* __restrict__ se_att_w2,  // 9*81
    const float* __restrict__ se_att_b2,  // 9
    float* __restrict__ ws)
{
    __shared__ __align__(16) unsigned short kqs[128 * 200];  // 51200 B [col][k]
    __shared__ float wseL[DD * HW_];                         //  2916 B wse[tau][p]
    __shared__ float bseL[HW_];
    __shared__ float w2L[DD * 96];                           //  3456 B
    __shared__ float tseL[96];

    const int pb = blockIdx.x;
    const int b = pb & 255;
    const int q = pb >> 8;
    const int c0 = q * 128;
    const int t = threadIdx.x;
    const float* xb = x + (size_t)b * CH;

    // ---- stage small weights ----
    for (int v = t; v < DD * HW_; v += 256) {
        int tau = v / 81, p = v - 81 * tau;
        wseL[tau * 81 + p] = se_key_w[p * 9 + tau];
    }
    if (t < HW_) bseL[t] = se_key_b[t];
    for (int v = t; v < DD * 96; v += 256) {
        int d = v / 96, row = v - 96 * d;
        w2L[v] = (row < 81) ? se_att_w2[d * 81 + row] : 0.f;
    }
    if (t < 96) tseL[t] = (t < 81) ? ws[WS_TSE + t] : 0.f;
    __syncthreads();

    // ---- build KQ^T tile: kqs[jl][k] for k in [0,200) ----
    // q-rows (k < 81): KQ[k][j] = x.flat[k*512 + j]   (coalesced reads)
    for (int v = t; v < 128 * 81; v += 256) {
        int k = v >> 7, jl = v & 127;
        kqs[jl * 200 + k] = f2h(xb[k * 512 + c0 + jl]);
    }
    // k-rows (81 <= k < 162): spectral depthwise conv along flat axis
    for (int v = t; v < 128 * 81; v += 256) {
        int kk = v >> 7, jl = v & 127;
        int e = kk * 512 + c0 + jl;
        int p = e % 81;
        float s = bseL[p];
        #pragma unroll
        for (int tau = 0; tau < 9; ++tau) {
            int flat = e + (tau - 4) * 81;
            if (flat >= 0 && flat < CH)
                s = fmaf(xb[flat], wseL[tau * 81 + p], s);
        }
        kqs[jl * 200 + 81 + kk] = f2h(s);
    }
    // zero pad rows 162..199 (W1f cols there are zero too; keep clean anyway)
    for (int v = t; v < 128 * 38; v += 256) {
        int k = v >> 7, jl = v & 127;
        kqs[jl * 200 + 162 + k] = 0;
    }
    __syncthreads();

    // ---- MFMA K-loop: C[96 x 128] = W1f[96 x 192] * KQ[192 x 128-slice] ----
    const int wv = t >> 6;          // wave 0..3, owns cols [c0+wv*32, +32)
    const int lane = t & 63;
    const int quad = lane >> 4;
    const int l15 = lane & 15;
    const unsigned short* w1f = (const unsigned short*)(ws + WS_W1F);

    f32x4 acc[6][2];
    #pragma unroll
    for (int m = 0; m < 6; ++m)
        #pragma unroll
        for (int n = 0; n < 2; ++n)
            acc[m][n] = (f32x4){0.f, 0.f, 0.f, 0.f};

    #pragma unroll 1
    for (int pass = 0; pass < 6; ++pass) {
        half8 bfr[2];
        #pragma unroll
        for (int n = 0; n < 2; ++n)
            bfr[n] = *(const half8*)&kqs[(wv * 32 + n * 16 + l15) * 200 + pass * 32 + quad * 8];
        #pragma unroll
        for (int m = 0; m < 6; ++m) {
            half8 afr = *(const half8*)&w1f[(m * 16 + l15) * 192 + pass * 32 + quad * 8];
            #pragma unroll
            for (int n = 0; n < 2; ++n)
                acc[m][n] = __builtin_amdgcn_mfma_f32_16x16x32_f16(afr, bfr[n], acc[m][n], 0, 0, 0);
        }
    }

    // ---- epilogue: relu(C + tse) -> fold 9x81 -> softmax -> ws ATT ----
    // Fully unrolled n-loop: every acc index is compile-time (rule #20).
    float* attout = ws + WS_ATT + (size_t)b * 4608;
    #pragma unroll
    for (int n = 0; n < 2; ++n) {
        float pd[9];
        #pragma unroll
        for (int d = 0; d < 9; ++d) pd[d] = 0.f;
        #pragma unroll
        for (int m = 0; m < 6; ++m) {
            #pragma unroll
            for (int reg = 0; reg < 4; ++reg) {
                int row = m * 16 + quad * 4 + reg;
                float z = fmaxf(acc[m][n][reg] + tseL[row], 0.f);
                #pragma unroll
                for (int d = 0; d < 9; ++d)
                    pd[d] = fmaf(w2L[d * 96 + row], z, pd[d]);
            }
        }
        #pragma unroll
        for (int d = 0; d < 9; ++d) {
            pd[d] += __shfl_xor(pd[d], 16, 64);
            pd[d] += __shfl_xor(pd[d], 32, 64);
        }
        if (quad == 0) {
            int j = c0 + wv * 32 + n * 16 + l15;
            float ad[9];
            #pragma unroll
            for (int d = 0; d < 9; ++d) ad[d] = pd[d] + se_att_b2[d];
            float mm = ad[0];
            #pragma unroll
            for (int d = 1; d < 9; ++d) mm = fmaxf(mm, ad[d]);
            float ls = 0.f;
            #pragma unroll
            for (int d = 0; d < 9; ++d) { ad[d] = __expf(ad[d] - mm); ls += ad[d]; }
            float inv = 1.f / ls;
            #pragma unroll
            for (int d = 0; d < 9; ++d) attout[d * 512 + j] = ad[d] * inv;
        }
    }
}

// ============== Kernel B: combine, block = (batch, 64-channel tile) =========
__global__ __launch_bounds__(256) void combine_kernel(
    const float* __restrict__ x,
    const float* __restrict__ alpha,
    const float* __restrict__ sa_key_w,   // 512*9
    const float* __restrict__ se_key_w,   // 81*9
    const float* __restrict__ se_key_b,   // 81
    const float* __restrict__ se_val_w,   // 512*9
    const float* __restrict__ se_val_b,   // 512
    const float* __restrict__ ws,
    float* __restrict__ out)
{
    __shared__ float xs[72 * 81];   // channels c0-4 .. c0+67 (zero-pad OOB)
    __shared__ float vs[72 * 81];   // depthwise-v plane (zero OOB, matches pad_v)
    __shared__ float wvL[72 * 9];
    __shared__ float bvL[72];
    __shared__ float wkL[64 * 9];
    __shared__ float s2L[64];
    __shared__ float t2L[64];
    __shared__ float wseL[81 * 9];
    __shared__ float bseL[81];
    __shared__ float attL[9 * 64];
    __shared__ float a2L[8 * 81];
    /* ~60.5 KB */

    const int bid = blockIdx.x;
    const int b = bid >> 3;
    const int tile = bid & 7;
    const int c0 = tile * 64;
    const int t = threadIdx.x;
    const int f0 = (c0 - 4) * 81;

    for (int idx = t; idx < 5832; idx += 256) {
        int g = f0 + idx;
        xs[idx] = (g >= 0 && g < CH) ? x[(size_t)b * CH + g] : 0.f;
    }
    for (int idx = t; idx < 648; idx += 256) {
        int cc = c0 - 4 + idx / 9;
        wvL[idx] = (cc >= 0 && cc < 512) ? se_val_w[cc * 9 + idx % 9] : 0.f;
    }
    if (t < 72) {
        int cc = c0 - 4 + t;
        bvL[t] = (cc >= 0 && cc < 512) ? se_val_b[cc] : 0.f;
    }
    for (int idx = t; idx < 576; idx += 256) wkL[idx] = sa_key_w[c0 * 9 + idx];
    if (t < 64) { s2L[t] = ws[WS_S2 + c0 + t]; t2L[t] = ws[WS_T2 + c0 + t]; }
    for (int idx = t; idx < 729; idx += 256) wseL[idx] = se_key_w[idx];
    if (t < 81) bseL[t] = se_key_b[t];
    for (int idx = t; idx < 576; idx += 256)
        attL[idx] = ws[WS_ATT + (size_t)b * 4608 + (idx >> 6) * 512 + c0 + (idx & 63)];
    for (int idx = t; idx < 648; idx += 256)
        a2L[idx] = ws[WS_A2 + (size_t)b * 5184 + tile * 648 + idx];
    __syncthreads();

    // depthwise-v plane (3x3 conv + bias), zero for OOB channels (= pad_v)
    for (int idx = t; idx < 5832; idx += 256) {
        int i = idx / 81, p = idx - 81 * i;
        int cc = c0 - 4 + i;
        float r = 0.f;
        if (cc >= 0 && cc < 512) {
            int y = p / 9, xx = p - 9 * (p / 9);
            float s = 0.f;
            #pragma unroll
            for (int ky = 0; ky < 3; ++ky) {
                int yy = y + ky - 1;
                if (yy < 0 || yy > 8) continue;
                #pragma unroll
                for (int kx = 0; kx < 3; ++kx) {
                    int xc = xx + kx - 1;
                    if (xc < 0 || xc > 8) continue;
                    s = fmaf(xs[i * 81 + yy * 9 + xc], wvL[i * 9 + ky * 3 + kx], s);
                }
            }
            r = s + bvL[i];
        }
        vs[idx] = r;
    }
    __syncthreads();

    const float av = alpha[0];
    float* outb = out + (size_t)b * CH + (size_t)c0 * 81;
    #pragma unroll 1
    for (int e = t; e < 5184; e += 256) {
        int cl = e / 81, p = e - 81 * cl;
        int y = p / 9, xx = p - 9 * y;
        // spatial key (3x3 dw conv -> bn -> relu)
        float sk = 0.f;
        #pragma unroll
        for (int ky = 0; ky < 3; ++ky) {
            int yy = y + ky - 1;
            if (yy < 0 || yy > 8) continue;
            #pragma unroll
            for (int kx = 0; kx < 3; ++kx) {
                int xc = xx + kx - 1;
                if (xc < 0 || xc > 8) continue;
                sk = fmaf(xs[(cl + 4) * 81 + yy * 9 + xc], wkL[cl * 9 + ky * 3 + kx], sk);
            }
        }
        float k1s = fmaxf(sk * s2L[cl] + t2L[cl], 0.f);
        // spectral attention combine
        float o1 = 0.f;
        #pragma unroll
        for (int d = 0; d < 9; ++d)
            o1 = fmaf(vs[(cl + d) * 81 + p], attL[d * 64 + cl], o1);
        // spectral key value (k1) added to out1
        float k1se = bseL[p];
        #pragma unroll
        for (int tau = 0; tau < 9; ++tau)
            k1se = fmaf(xs[(cl + tau) * 81 + p], wseL[p * 9 + tau], k1se);
        float out2 = k1s + a2L[(cl >> 3) * 81 + p] * xs[(cl + 4) * 81 + p];
        outb[cl * 81 + p] = av * (o1 + k1se) + (1.f - av) * out2;
    }
}

extern "C" void kernel_launch(void* const* d_in, const int* in_sizes, int n_in,
                              void* d_out, int out_size, void* d_ws, size_t ws_size,
                              hipStream_t stream) {
    const float* x          = (const float*)d_in[0];
    const float* alpha      = (const float*)d_in[1];
    const float* sa_key_w   = (const float*)d_in[2];
    const float* sa_key_bn  = (const float*)d_in[3];
    const float* sa_att_w1  = (const float*)d_in[4];
    const float* sa_att_bn  = (const float*)d_in[5];
    const float* sa_att_w2  = (const float*)d_in[6];
    const float* sa_att_b2  = (const float*)d_in[7];
    const float* se_key_w   = (const float*)d_in[8];
    const float* se_key_b   = (const float*)d_in[9];
    const float* se_att_w1  = (const float*)d_in[10];
    const float* se_att_bn  = (const float*)d_in[11];
    const float* se_att_w2  = (const float*)d_in[12];
    const float* se_att_b2  = (const float*)d_in[13];
    const float* se_val_w   = (const float*)d_in[14];
    const float* se_val_b   = (const float*)d_in[15];
    float* ws = (float*)d_ws;
    float* outp = (float*)d_out;

    prep_kernel<<<(PREP_N + 255) / 256, 256, 0, stream>>>(
        se_att_w1, se_att_bn, sa_key_bn, sa_att_w1, sa_att_bn, ws);
    sa_kernel<<<BSZ * 4, 256, 0, stream>>>(
        x, sa_key_w, sa_att_w2, sa_att_b2, ws);
    se_kernel<<<BSZ * 4, 256, 0, stream>>>(
        x, se_key_w, se_key_b, se_att_w2, se_att_b2, ws);
    combine_kernel<<<BSZ * 8, 256, 0, stream>>>(
        x, alpha, sa_key_w, se_key_w, se_key_b, se_val_w, se_val_b, ws, outp);
}

// Round 3
// 438.965 us; speedup vs baseline: 1.6856x; 1.2279x over previous
//
#include <hip/hip_runtime.h>
#include <hip/hip_fp16.h>

#define BSZ 256
#define CCH 512
#define HW_ 81
#define DD 9
#define CH 41472   /* CCH*HW_ */

/* ws layout (floats) */
#define WS_W1T   0        /* [162][81] folded+transposed se_att_w1 (legacy, unused) */
#define WS_TSE   13122    /* [81]  folded se_att bias */
#define WS_S2    13203    /* [512] sa_key bn scale */
#define WS_T2    13715    /* [512] sa_key bn bias */
#define WS_W1S   14227    /* [512][16] folded sa_att_w1 */
#define WS_T1    22419    /* [512] folded sa_att bias */
#define WS_A2    22932    /* [256][64][81] SaMCA attention */
#define WS_ATT   1350036  /* [256][9][512] SeMCA attention */
#define WS_W1F   2529684  /* [96][192] fp16 folded se_att_w1, zero-padded (ushorts) */
#define WS_TOTALP 22931   /* params region end */
#define PREP_N   41363    /* 22931 + 96*192/2 */

typedef _Float16 half8 __attribute__((ext_vector_type(8)));
typedef float f32x4 __attribute__((ext_vector_type(4)));

__device__ __forceinline__ float h2f(unsigned short u) {
    return __half2float(__ushort_as_half(u));
}
__device__ __forceinline__ unsigned short f2h(float f) {
    return __half_as_ushort(__float2half(f));
}

__global__ void prep_kernel(const float* __restrict__ se_att_w1,  // 81*162
                            const float* __restrict__ se_att_bn,  // 4*81
                            const float* __restrict__ sa_key_bn,  // 4*512
                            const float* __restrict__ sa_att_w1,  // 512*16
                            const float* __restrict__ sa_att_bn,  // 4*512
                            float* __restrict__ ws) {
    int idx = blockIdx.x * blockDim.x + threadIdx.x;
    if (idx < 13122) {
        int r = idx / 81, o = idx % 81;
        float g = se_att_bn[o], v = se_att_bn[243 + o];
        float s = g * rsqrtf(v + 1e-5f);
        ws[WS_W1T + idx] = se_att_w1[o * 162 + r] * s;
    } else if (idx < 13203) {
        int o = idx - 13122;
        float g = se_att_bn[o], b = se_att_bn[81 + o], m = se_att_bn[162 + o], v = se_att_bn[243 + o];
        float s = g * rsqrtf(v + 1e-5f);
        ws[WS_TSE + o] = b - m * s;
    } else if (idx < 13715) {
        int c = idx - 13203;
        float g = sa_key_bn[c], v = sa_key_bn[1536 + c];
        ws[WS_S2 + c] = g * rsqrtf(v + 1e-5f);
    } else if (idx < 14227) {
        int c = idx - 13715;
        float g = sa_key_bn[c], b = sa_key_bn[512 + c], m = sa_key_bn[1024 + c], v = sa_key_bn[1536 + c];
        float s = g * rsqrtf(v + 1e-5f);
        ws[WS_T2 + c] = b - m * s;
    } else if (idx < 22419) {
        int e = idx - 14227;
        int o = e >> 4;
        float g = sa_att_bn[o], v = sa_att_bn[1536 + o];
        float s = g * rsqrtf(v + 1e-5f);
        ws[WS_W1S + e] = sa_att_w1[e] * s;
    } else if (idx < WS_TOTALP) {
        int o = idx - 22419;
        float g = sa_att_bn[o], b = sa_att_bn[512 + o], m = sa_att_bn[1024 + o], v = sa_att_bn[1536 + o];
        float s = g * rsqrtf(v + 1e-5f);
        ws[WS_T1 + o] = b - m * s;
    } else if (idx < PREP_N) {
        // fp16 folded W1, padded [96][192] (two ushorts per float slot)
        int e2 = (idx - WS_TOTALP) * 2;
        unsigned int packed = 0;
        #pragma unroll
        for (int q = 0; q < 2; ++q) {
            int e = e2 + q;
            int row = e / 192, k = e - row * 192;
            unsigned short val = 0;
            if (row < 81 && k < 162) {
                float g = se_att_bn[row], v = se_att_bn[243 + row];
                float s = g * rsqrtf(v + 1e-5f);
                val = f2h(se_att_w1[row * 162 + k] * s);
            }
            packed |= ((unsigned int)val) << (16 * q);
        }
        ((unsigned int*)(ws + WS_W1F))[idx - WS_TOTALP] = packed;
    }
}

// ======== Kernel SA: SaMCA attention, grid = (batch x 4 ch-quarters) ========
// Two-pass, low-VGPR form (round-1 fix; no spill, VGPR~96).
__global__ __launch_bounds__(256) void sa_kernel(
    const float* __restrict__ x,
    const float* __restrict__ sa_key_w,   // 512*9
    const float* __restrict__ sa_att_w2,  // 64*8
    const float* __restrict__ sa_att_b2,  // 64
    float* __restrict__ ws)
{
    __shared__ __align__(16) unsigned short xbh[128 * HW_]; // 20736 B fp16 x quarter
    __shared__ float kvf[128 * HW_];                        // 41472 B f32 kv plane
    __shared__ unsigned short wkbL[128 * DD];               //  2304 B
    __shared__ float s2L[128];
    __shared__ float t2L[128];
    __shared__ float w1sL[128 * 16];                        //  8192 B
    __shared__ float saw2L[128];
    __shared__ float b2L[16];
    __shared__ float t1L[128];
    /* total ~74.9 KB */

    const int bid = blockIdx.x;
    const int b = bid >> 2;
    const int qr = bid & 3;
    const int c0 = qr * 128;
    const int t = threadIdx.x;

    // ---- stage ----
    {
        const float4* x4 = (const float4*)(x + (size_t)b * CH + (size_t)c0 * 81);
        for (int v = t; v < 128 * 81 / 4; v += 256) {
            float4 q = x4[v];
            ushort4 s4;
            s4.x = f2h(q.x); s4.y = f2h(q.y); s4.z = f2h(q.z); s4.w = f2h(q.w);
            *(ushort4*)(&xbh[4 * v]) = s4;
        }
        for (int v = t; v < 128 * DD; v += 256) wkbL[v] = f2h(sa_key_w[c0 * 9 + v]);
        if (t < 128) {
            s2L[t] = ws[WS_S2 + c0 + t];
            t2L[t] = ws[WS_T2 + c0 + t];
            saw2L[t] = sa_att_w2[c0 + t];
            t1L[t] = ws[WS_T1 + c0 + t];
        }
        for (int v = t; v < 128 * 16; v += 256) w1sL[v] = ws[WS_W1S + c0 * 16 + v];
        if (t < 16) b2L[t] = sa_att_b2[qr * 16 + t];
    }
    __syncthreads();

    // ---- Pass A: kv = relu(bn(dwconv3x3(x))), f32 into LDS ----
    #pragma unroll 2
    for (int idx = t; idx < 128 * 81; idx += 256) {
        int c = idx / 81, p = idx - 81 * c;
        int y = p / 9, xx = p - 9 * y;
        float conv = 0.f;
        #pragma unroll
        for (int ky = 0; ky < 3; ++ky) {
            int yy = y + ky - 1;
            if (yy < 0 || yy > 8) continue;
            #pragma unroll
            for (int kx = 0; kx < 3; ++kx) {
                int xc = xx + kx - 1;
                if (xc < 0 || xc > 8) continue;
                conv = fmaf(h2f(xbh[c * 81 + yy * 9 + xc]),
                            h2f(wkbL[c * 9 + ky * 3 + kx]), conv);
            }
        }
        kvf[idx] = fmaxf(conv * s2L[c] + t2L[c], 0.f);
    }
    __syncthreads();

    // ---- Pass B: attention logits + softmax ----
    // 16 groups x 16 lanes; lane sub handles pixels p = sub + 16k, k<6.
    {
        const int g = t >> 4, sub = t & 15;
        const int cb = g * 8;                    // local channel base
        float z[8][6];
        #pragma unroll
        for (int o = 0; o < 8; ++o)
            #pragma unroll
            for (int k = 0; k < 6; ++k)
                z[o][k] = t1L[cb + o];

        #pragma unroll 1
        for (int j = 0; j < 8; ++j) {
            float wk[8], wx[8];
            #pragma unroll
            for (int o = 0; o < 8; ++o) {
                wk[o] = w1sL[(cb + o) * 16 + 2 * j];
                wx[o] = w1sL[(cb + o) * 16 + 2 * j + 1];
            }
            const int rowb = (cb + j) * 81;
            #pragma unroll
            for (int k = 0; k < 6; ++k) {
                int p = sub + 16 * k;
                if (p > 80) p = 80;              // clamp; masked at softmax
                float kv = kvf[rowb + p];
                float xv = h2f(xbh[rowb + p]);
                #pragma unroll
                for (int o = 0; o < 8; ++o) {
                    z[o][k] = fmaf(wk[o], kv, z[o][k]);
                    z[o][k] = fmaf(wx[o], xv, z[o][k]);
                }
            }
        }

        float a2v[6];
        const float b2g = b2L[g];
        #pragma unroll
        for (int k = 0; k < 6; ++k) {
            float s = b2g;
            #pragma unroll
            for (int o = 0; o < 8; ++o)
                s = fmaf(saw2L[cb + o], fmaxf(z[o][k], 0.f), s);
            int p = sub + 16 * k;
            a2v[k] = (p < 81) ? s : -1e30f;
        }

        // softmax over the 81 pixels (16 lanes x 6 slots, masked)
        float m = a2v[0];
        #pragma unroll
        for (int k = 1; k < 6; ++k) m = fmaxf(m, a2v[k]);
        #pragma unroll
        for (int off = 1; off < 16; off <<= 1) m = fmaxf(m, __shfl_xor(m, off, 64));
        float ls = 0.f;
        float ev[6];
        #pragma unroll
        for (int k = 0; k < 6; ++k) { ev[k] = __expf(a2v[k] - m); ls += ev[k]; }
        #pragma unroll
        for (int off = 1; off < 16; off <<= 1) ls += __shfl_xor(ls, off, 64);
        float inv = 1.f / ls;

        float* a2out = ws + WS_A2 + (size_t)b * 5184 + (size_t)(qr * 16 + g) * 81;
        #pragma unroll
        for (int k = 0; k < 6; ++k) {
            int p = sub + 16 * k;
            if (p < 81) a2out[p] = ev[k] * inv;
        }
    }
}

// ======== Kernel SE: SeMCA attention via MFMA, grid = 256 (1 block/batch) ===
// Round-2 version was latency-bound (193us, VALUBusy 12.7%, MfmaUtil 1%):
// the 9-tap spectral conv read global x per tap inside 41 serial loop
// iterations/thread -> every iteration ate an L2 round trip with only
// 2 waves/SIMD to hide it. Now: stage the WHOLE batch x as fp16 in LDS
// (81 KB), build KQ^T + conv purely from LDS, loop the 4 column-quarters
// internally. 512 thr, LDS ~141 KB -> 1 block/CU (8 waves), grid 256 = 1
// block per CU, x read exactly once per batch.
__global__ __launch_bounds__(512) void se_kernel(
    const float* __restrict__ x,
    const float* __restrict__ se_key_w,   // 81*9
    const float* __restrict__ se_key_b,   // 81
    const float* __restrict__ se_att_w2,  // 9*81
    const float* __restrict__ se_att_b2,  // 9
    float* __restrict__ ws)
{
    __shared__ __align__(16) unsigned short xbh[CH];         // 82944 B fp16 x[b]
    __shared__ __align__(16) unsigned short kqs[128 * 200];  // 51200 B [col][k]
    __shared__ float wseL[DD * HW_];                         //  2916 B wse[tau][p]
    __shared__ float bseL[HW_];
    __shared__ float w2L[DD * 96];                           //  3456 B
    __shared__ float tseL[96];
    /* total ~141.2 KB */

    const int b = blockIdx.x;
    const int t = threadIdx.x;
    const float* xb = x + (size_t)b * CH;

    // ---- stage small weights ----
    for (int v = t; v < DD * HW_; v += 512) {
        int tau = v / 81, p = v - 81 * tau;
        wseL[tau * 81 + p] = se_key_w[p * 9 + tau];
    }
    if (t < HW_) bseL[t] = se_key_b[t];
    for (int v = t; v < DD * 96; v += 512) {
        int d = v / 96, row = v - 96 * d;
        w2L[v] = (row < 81) ? se_att_w2[d * 81 + row] : 0.f;
    }
    if (t < 96) tseL[t] = (t < 81) ? ws[WS_TSE + t] : 0.f;
    // zero-pad kqs rows 162..199 ONCE (never rewritten; must not be garbage
    // since fp16 garbage could be Inf/NaN -> 0*Inf = NaN in MFMA)
    for (int v = t; v < 128 * 38; v += 512) {
        int k = v >> 7, jl = v & 127;
        kqs[jl * 200 + 162 + k] = 0;
    }
    // ---- stage x -> fp16 LDS (coalesced float4, batched for MLP) ----
    {
        const float4* x4 = (const float4*)xb;
        #pragma unroll 4
        for (int v = t; v < CH / 4; v += 512) {
            float4 q = x4[v];
            ushort4 s4;
            s4.x = f2h(q.x); s4.y = f2h(q.y); s4.z = f2h(q.z); s4.w = f2h(q.w);
            *(ushort4*)(&xbh[4 * v]) = s4;
        }
    }
    __syncthreads();

    const int wv = t >> 6;          // wave 0..7, owns 16 cols per quarter
    const int lane = t & 63;
    const int quad = lane >> 4;
    const int l15 = lane & 15;
    const unsigned short* w1f = (const unsigned short*)(ws + WS_W1F);
    float* attout = ws + WS_ATT + (size_t)b * 4608;

    #pragma unroll 1
    for (int q = 0; q < 4; ++q) {
        const int c0 = q * 128;
        if (q) __syncthreads();     // prev quarter's frag reads done

        // build q-rows (k < 81): pure LDS transpose copy
        for (int v = t; v < 128 * 81; v += 512) {
            int k = v >> 7, jl = v & 127;
            kqs[jl * 200 + k] = xbh[k * 512 + c0 + jl];
        }
        // build k-rows (81 <= k < 162): 9-tap spectral conv, all from LDS
        for (int v = t; v < 128 * 81; v += 512) {
            int kk = v >> 7, jl = v & 127;
            int e = kk * 512 + c0 + jl;
            int p = e % 81;
            float s = bseL[p];
            #pragma unroll
            for (int tau = 0; tau < 9; ++tau) {
                int flat = e + (tau - 4) * 81;
                if (flat >= 0 && flat < CH)
                    s = fmaf(h2f(xbh[flat]), wseL[tau * 81 + p], s);
            }
            kqs[jl * 200 + 81 + kk] = f2h(s);
        }
        __syncthreads();

        // MFMA: C[96 x 128] = W1f[96 x 192] * KQ[192 x 128]
        f32x4 acc[6];
        #pragma unroll
        for (int m = 0; m < 6; ++m) acc[m] = (f32x4){0.f, 0.f, 0.f, 0.f};

        #pragma unroll 1
        for (int pass = 0; pass < 6; ++pass) {
            half8 bfr = *(const half8*)&kqs[(wv * 16 + l15) * 200 + pass * 32 + quad * 8];
            #pragma unroll
            for (int m = 0; m < 6; ++m) {
                half8 afr = *(const half8*)&w1f[(m * 16 + l15) * 192 + pass * 32 + quad * 8];
                acc[m] = __builtin_amdgcn_mfma_f32_16x16x32_f16(afr, bfr, acc[m], 0, 0, 0);
            }
        }

        // epilogue: relu(C + tse) -> fold 9x81 -> softmax -> ws ATT
        float pd[9];
        #pragma unroll
        for (int d = 0; d < 9; ++d) pd[d] = 0.f;
        #pragma unroll
        for (int m = 0; m < 6; ++m) {
            #pragma unroll
            for (int reg = 0; reg < 4; ++reg) {
                int row = m * 16 + quad * 4 + reg;
                float z = fmaxf(acc[m][reg] + tseL[row], 0.f);
                #pragma unroll
                for (int d = 0; d < 9; ++d)
                    pd[d] = fmaf(w2L[d * 96 + row], z, pd[d]);
            }
        }
        #pragma unroll
        for (int d = 0; d < 9; ++d) {
            pd[d] += __shfl_xor(pd[d], 16, 64);
            pd[d] += __shfl_xor(pd[d], 32, 64);
        }
        if (quad == 0) {
            int j = c0 + wv * 16 + l15;
            float ad[9];
            #pragma unroll
            for (int d = 0; d < 9; ++d) ad[d] = pd[d] + se_att_b2[d];
            float mm = ad[0];
            #pragma unroll
            for (int d = 1; d < 9; ++d) mm = fmaxf(mm, ad[d]);
            float ls = 0.f;
            #pragma unroll
            for (int d = 0; d < 9; ++d) { ad[d] = __expf(ad[d] - mm); ls += ad[d]; }
            float inv = 1.f / ls;
            #pragma unroll
            for (int d = 0; d < 9; ++d) attout[d * 512 + j] = ad[d] * inv;
        }
    }
}

// ============== Kernel B: combine, block = (batch, 64-channel tile) =========
__global__ __launch_bounds__(256) void combine_kernel(
    const float* __restrict__ x,
    const float* __restrict__ alpha,
    const float* __restrict__ sa_key_w,   // 512*9
    const float* __restrict__ se_key_w,   // 81*9
    const float* __restrict__ se_key_b,   // 81
    const float* __restrict__ se_val_w,   // 512*9
    const float* __restrict__ se_val_b,   // 512
    const float* __restrict__ ws,
    float* __restrict__ out)
{
    __shared__ float xs[72 * 81];   // channels c0-4 .. c0+67 (zero-pad OOB)
    __shared__ float vs[72 * 81];   // depthwise-v plane (zero OOB, matches pad_v)
    __shared__ float wvL[72 * 9];
    __shared__ float bvL[72];
    __shared__ float wkL[64 * 9];
    __shared__ float s2L[64];
    __shared__ float t2L[64];
    __shared__ float wseL[81 * 9];
    __shared__ float bseL[81];
    __shared__ float attL[9 * 64];
    __shared__ float a2L[8 * 81];
    /* ~60.5 KB */

    const int bid = blockIdx.x;
    const int b = bid >> 3;
    const int tile = bid & 7;
    const int c0 = tile * 64;
    const int t = threadIdx.x;
    const int f0 = (c0 - 4) * 81;

    for (int idx = t; idx < 5832; idx += 256) {
        int g = f0 + idx;
        xs[idx] = (g >= 0 && g < CH) ? x[(size_t)b * CH + g] : 0.f;
    }
    for (int idx = t; idx < 648; idx += 256) {
        int cc = c0 - 4 + idx / 9;
        wvL[idx] = (cc >= 0 && cc < 512) ? se_val_w[cc * 9 + idx % 9] : 0.f;
    }
    if (t < 72) {
        int cc = c0 - 4 + t;
        bvL[t] = (cc >= 0 && cc < 512) ? se_val_b[cc] : 0.f;
    }
    for (int idx = t; idx < 576; idx += 256) wkL[idx] = sa_key_w[c0 * 9 + idx];
    if (t < 64) { s2L[t] = ws[WS_S2 + c0 + t]; t2L[t] = ws[WS_T2 + c0 + t]; }
    for (int idx = t; idx < 729; idx += 256) wseL[idx] = se_key_w[idx];
    if (t < 81) bseL[t] = se_key_b[t];
    for (int idx = t; idx < 576; idx += 256)
        attL[idx] = ws[WS_ATT + (size_t)b * 4608 + (idx >> 6) * 512 + c0 + (idx & 63)];
    for (int idx = t; idx < 648; idx += 256)
        a2L[idx] = ws[WS_A2 + (size_t)b * 5184 + tile * 648 + idx];
    __syncthreads();

    // depthwise-v plane (3x3 conv + bias), zero for OOB channels (= pad_v)
    for (int idx = t; idx < 5832; idx += 256) {
        int i = idx / 81, p = idx - 81 * i;
        int cc = c0 - 4 + i;
        float r = 0.f;
        if (cc >= 0 && cc < 512) {
            int y = p / 9, xx = p - 9 * (p / 9);
            float s = 0.f;
            #pragma unroll
            for (int ky = 0; ky < 3; ++ky) {
                int yy = y + ky - 1;
                if (yy < 0 || yy > 8) continue;
                #pragma unroll
                for (int kx = 0; kx < 3; ++kx) {
                    int xc = xx + kx - 1;
                    if (xc < 0 || xc > 8) continue;
                    s = fmaf(xs[i * 81 + yy * 9 + xc], wvL[i * 9 + ky * 3 + kx], s);
                }
            }
            r = s + bvL[i];
        }
        vs[idx] = r;
    }
    __syncthreads();

    const float av = alpha[0];
    float* outb = out + (size_t)b * CH + (size_t)c0 * 81;
    #pragma unroll 1
    for (int e = t; e < 5184; e += 256) {
        int cl = e / 81, p = e - 81 * cl;
        int y = p / 9, xx = p - 9 * y;
        // spatial key (3x3 dw conv -> bn -> relu)
        float sk = 0.f;
        #pragma unroll
        for (int ky = 0; ky < 3; ++ky) {
            int yy = y + ky - 1;
            if (yy < 0 || yy > 8) continue;
            #pragma unroll
            for (int kx = 0; kx < 3; ++kx) {
                int xc = xx + kx - 1;
                if (xc < 0 || xc > 8) continue;
                sk = fmaf(xs[(cl + 4) * 81 + yy * 9 + xc], wkL[cl * 9 + ky * 3 + kx], sk);
            }
        }
        float k1s = fmaxf(sk * s2L[cl] + t2L[cl], 0.f);
        // spectral attention combine
        float o1 = 0.f;
        #pragma unroll
        for (int d = 0; d < 9; ++d)
            o1 = fmaf(vs[(cl + d) * 81 + p], attL[d * 64 + cl], o1);
        // spectral key value (k1) added to out1
        float k1se = bseL[p];
        #pragma unroll
        for (int tau = 0; tau < 9; ++tau)
            k1se = fmaf(xs[(cl + tau) * 81 + p], wseL[p * 9 + tau], k1se);
        float out2 = k1s + a2L[(cl >> 3) * 81 + p] * xs[(cl + 4) * 81 + p];
        outb[cl * 81 + p] = av * (o1 + k1se) + (1.f - av) * out2;
    }
}

extern "C" void kernel_launch(void* const* d_in, const int* in_sizes, int n_in,
                              void* d_out, int out_size, void* d_ws, size_t ws_size,
                              hipStream_t stream) {
    const float* x          = (const float*)d_in[0];
    const float* alpha      = (const float*)d_in[1];
    const float* sa_key_w   = (const float*)d_in[2];
    const float* sa_key_bn  = (const float*)d_in[3];
    const float* sa_att_w1  = (const float*)d_in[4];
    const float* sa_att_bn  = (const float*)d_in[5];
    const float* sa_att_w2  = (const float*)d_in[6];
    const float* sa_att_b2  = (const float*)d_in[7];
    const float* se_key_w   = (const float*)d_in[8];
    const float* se_key_b   = (const float*)d_in[9];
    const float* se_att_w1  = (const float*)d_in[10];
    const float* se_att_bn  = (const float*)d_in[11];
    const float* se_att_w2  = (const float*)d_in[12];
    const float* se_att_b2  = (const float*)d_in[13];
    const float* se_val_w   = (const float*)d_in[14];
    const float* se_val_b   = (const float*)d_in[15];
    float* ws = (float*)d_ws;
    float* outp = (float*)d_out;

    prep_kernel<<<(PREP_N + 255) / 256, 256, 0, stream>>>(
        se_att_w1, se_att_bn, sa_key_bn, sa_att_w1, sa_att_bn, ws);
    sa_kernel<<<BSZ * 4, 256, 0, stream>>>(
        x, sa_key_w, sa_att_w2, sa_att_b2, ws);
    se_kernel<<<BSZ, 512, 0, stream>>>(
        x, se_key_w, se_key_b, se_att_w2, se_att_b2, ws);
    combine_kernel<<<BSZ * 8, 256, 0, stream>>>(
        x, alpha, sa_key_w, se_key_w, se_key_b, se_val_w, se_val_b, ws, outp);
}

// Round 4
// 360.840 us; speedup vs baseline: 2.0505x; 1.2165x over previous
//
#include <hip/hip_runtime.h>
#include <hip/hip_fp16.h>

#define BSZ 256
#define CCH 512
#define HW_ 81
#define DD 9
#define CH 41472   /* CCH*HW_ */

/* ws layout (floats) */
#define WS_W1T   0        /* [162][81] folded+transposed se_att_w1 (legacy, unused) */
#define WS_TSE   13122    /* [81]  folded se_att bias */
#define WS_S2    13203    /* [512] sa_key bn scale */
#define WS_T2    13715    /* [512] sa_key bn bias */
#define WS_W1S   14227    /* [512][16] folded sa_att_w1 */
#define WS_T1    22419    /* [512] folded sa_att bias */
#define WS_A2    22932    /* [256][64][81] SaMCA attention */
#define WS_ATT   1350036  /* [256][9][512] SeMCA attention */
#define WS_W1F   2529684  /* [96][192] fp16 folded se_att_w1, zero-padded (ushorts) */
#define WS_TOTALP 22931   /* params region end */
#define PREP_N   41363    /* 22931 + 96*192/2 */

typedef _Float16 half8 __attribute__((ext_vector_type(8)));
typedef float f32x4 __attribute__((ext_vector_type(4)));

__device__ __forceinline__ float h2f(unsigned short u) {
    return __half2float(__ushort_as_half(u));
}
__device__ __forceinline__ unsigned short f2h(float f) {
    return __half_as_ushort(__float2half(f));
}

__global__ void prep_kernel(const float* __restrict__ se_att_w1,  // 81*162
                            const float* __restrict__ se_att_bn,  // 4*81
                            const float* __restrict__ sa_key_bn,  // 4*512
                            const float* __restrict__ sa_att_w1,  // 512*16
                            const float* __restrict__ sa_att_bn,  // 4*512
                            float* __restrict__ ws) {
    int idx = blockIdx.x * blockDim.x + threadIdx.x;
    if (idx < 13122) {
        int r = idx / 81, o = idx % 81;
        float g = se_att_bn[o], v = se_att_bn[243 + o];
        float s = g * rsqrtf(v + 1e-5f);
        ws[WS_W1T + idx] = se_att_w1[o * 162 + r] * s;
    } else if (idx < 13203) {
        int o = idx - 13122;
        float g = se_att_bn[o], b = se_att_bn[81 + o], m = se_att_bn[162 + o], v = se_att_bn[243 + o];
        float s = g * rsqrtf(v + 1e-5f);
        ws[WS_TSE + o] = b - m * s;
    } else if (idx < 13715) {
        int c = idx - 13203;
        float g = sa_key_bn[c], v = sa_key_bn[1536 + c];
        ws[WS_S2 + c] = g * rsqrtf(v + 1e-5f);
    } else if (idx < 14227) {
        int c = idx - 13715;
        float g = sa_key_bn[c], b = sa_key_bn[512 + c], m = sa_key_bn[1024 + c], v = sa_key_bn[1536 + c];
        float s = g * rsqrtf(v + 1e-5f);
        ws[WS_T2 + c] = b - m * s;
    } else if (idx < 22419) {
        int e = idx - 14227;
        int o = e >> 4;
        float g = sa_att_bn[o], v = sa_att_bn[1536 + o];
        float s = g * rsqrtf(v + 1e-5f);
        ws[WS_W1S + e] = sa_att_w1[e] * s;
    } else if (idx < WS_TOTALP) {
        int o = idx - 22419;
        float g = sa_att_bn[o], b = sa_att_bn[512 + o], m = sa_att_bn[1024 + o], v = sa_att_bn[1536 + o];
        float s = g * rsqrtf(v + 1e-5f);
        ws[WS_T1 + o] = b - m * s;
    } else if (idx < PREP_N) {
        // fp16 folded W1, padded [96][192] (two ushorts per float slot)
        int e2 = (idx - WS_TOTALP) * 2;
        unsigned int packed = 0;
        #pragma unroll
        for (int q = 0; q < 2; ++q) {
            int e = e2 + q;
            int row = e / 192, k = e - row * 192;
            unsigned short val = 0;
            if (row < 81 && k < 162) {
                float g = se_att_bn[row], v = se_att_bn[243 + row];
                float s = g * rsqrtf(v + 1e-5f);
                val = f2h(se_att_w1[row * 162 + k] * s);
            }
            packed |= ((unsigned int)val) << (16 * q);
        }
        ((unsigned int*)(ws + WS_W1F))[idx - WS_TOTALP] = packed;
    }
}

// ======== Kernel SA: SaMCA attention, grid = (batch x 4 ch-quarters) ========
// Two-pass, low-VGPR form (round-1 fix; no spill, VGPR~96).
__global__ __launch_bounds__(256) void sa_kernel(
    const float* __restrict__ x,
    const float* __restrict__ sa_key_w,   // 512*9
    const float* __restrict__ sa_att_w2,  // 64*8
    const float* __restrict__ sa_att_b2,  // 64
    float* __restrict__ ws)
{
    __shared__ __align__(16) unsigned short xbh[128 * HW_]; // 20736 B fp16 x quarter
    __shared__ float kvf[128 * HW_];                        // 41472 B f32 kv plane
    __shared__ unsigned short wkbL[128 * DD];               //  2304 B
    __shared__ float s2L[128];
    __shared__ float t2L[128];
    __shared__ float w1sL[128 * 16];                        //  8192 B
    __shared__ float saw2L[128];
    __shared__ float b2L[16];
    __shared__ float t1L[128];
    /* total ~74.9 KB */

    const int bid = blockIdx.x;
    const int b = bid >> 2;
    const int qr = bid & 3;
    const int c0 = qr * 128;
    const int t = threadIdx.x;

    // ---- stage ----
    {
        const float4* x4 = (const float4*)(x + (size_t)b * CH + (size_t)c0 * 81);
        for (int v = t; v < 128 * 81 / 4; v += 256) {
            float4 q = x4[v];
            ushort4 s4;
            s4.x = f2h(q.x); s4.y = f2h(q.y); s4.z = f2h(q.z); s4.w = f2h(q.w);
            *(ushort4*)(&xbh[4 * v]) = s4;
        }
        for (int v = t; v < 128 * DD; v += 256) wkbL[v] = f2h(sa_key_w[c0 * 9 + v]);
        if (t < 128) {
            s2L[t] = ws[WS_S2 + c0 + t];
            t2L[t] = ws[WS_T2 + c0 + t];
            saw2L[t] = sa_att_w2[c0 + t];
            t1L[t] = ws[WS_T1 + c0 + t];
        }
        for (int v = t; v < 128 * 16; v += 256) w1sL[v] = ws[WS_W1S + c0 * 16 + v];
        if (t < 16) b2L[t] = sa_att_b2[qr * 16 + t];
    }
    __syncthreads();

    // ---- Pass A: kv = relu(bn(dwconv3x3(x))), f32 into LDS ----
    #pragma unroll 2
    for (int idx = t; idx < 128 * 81; idx += 256) {
        int c = idx / 81, p = idx - 81 * c;
        int y = p / 9, xx = p - 9 * y;
        float conv = 0.f;
        #pragma unroll
        for (int ky = 0; ky < 3; ++ky) {
            int yy = y + ky - 1;
            if (yy < 0 || yy > 8) continue;
            #pragma unroll
            for (int kx = 0; kx < 3; ++kx) {
                int xc = xx + kx - 1;
                if (xc < 0 || xc > 8) continue;
                conv = fmaf(h2f(xbh[c * 81 + yy * 9 + xc]),
                            h2f(wkbL[c * 9 + ky * 3 + kx]), conv);
            }
        }
        kvf[idx] = fmaxf(conv * s2L[c] + t2L[c], 0.f);
    }
    __syncthreads();

    // ---- Pass B: attention logits + softmax ----
    // 16 groups x 16 lanes; lane sub handles pixels p = sub + 16k, k<6.
    {
        const int g = t >> 4, sub = t & 15;
        const int cb = g * 8;                    // local channel base
        float z[8][6];
        #pragma unroll
        for (int o = 0; o < 8; ++o)
            #pragma unroll
            for (int k = 0; k < 6; ++k)
                z[o][k] = t1L[cb + o];

        #pragma unroll 1
        for (int j = 0; j < 8; ++j) {
            float wk[8], wx[8];
            #pragma unroll
            for (int o = 0; o < 8; ++o) {
                wk[o] = w1sL[(cb + o) * 16 + 2 * j];
                wx[o] = w1sL[(cb + o) * 16 + 2 * j + 1];
            }
            const int rowb = (cb + j) * 81;
            #pragma unroll
            for (int k = 0; k < 6; ++k) {
                int p = sub + 16 * k;
                if (p > 80) p = 80;              // clamp; masked at softmax
                float kv = kvf[rowb + p];
                float xv = h2f(xbh[rowb + p]);
                #pragma unroll
                for (int o = 0; o < 8; ++o) {
                    z[o][k] = fmaf(wk[o], kv, z[o][k]);
                    z[o][k] = fmaf(wx[o], xv, z[o][k]);
                }
            }
        }

        float a2v[6];
        const float b2g = b2L[g];
        #pragma unroll
        for (int k = 0; k < 6; ++k) {
            float s = b2g;
            #pragma unroll
            for (int o = 0; o < 8; ++o)
                s = fmaf(saw2L[cb + o], fmaxf(z[o][k], 0.f), s);
            int p = sub + 16 * k;
            a2v[k] = (p < 81) ? s : -1e30f;
        }

        // softmax over the 81 pixels (16 lanes x 6 slots, masked)
        float m = a2v[0];
        #pragma unroll
        for (int k = 1; k < 6; ++k) m = fmaxf(m, a2v[k]);
        #pragma unroll
        for (int off = 1; off < 16; off <<= 1) m = fmaxf(m, __shfl_xor(m, off, 64));
        float ls = 0.f;
        float ev[6];
        #pragma unroll
        for (int k = 0; k < 6; ++k) { ev[k] = __expf(a2v[k] - m); ls += ev[k]; }
        #pragma unroll
        for (int off = 1; off < 16; off <<= 1) ls += __shfl_xor(ls, off, 64);
        float inv = 1.f / ls;

        float* a2out = ws + WS_A2 + (size_t)b * 5184 + (size_t)(qr * 16 + g) * 81;
        #pragma unroll
        for (int k = 0; k < 6; ++k) {
            int p = sub + 16 * k;
            if (p < 81) a2out[p] = ev[k] * inv;
        }
    }
}

// ======== Kernel SE: SeMCA attention via MFMA, grid = 256 (1 block/batch) ===
// Whole-batch x staged fp16 in LDS; KQ^T + spectral conv built from LDS;
// 4 column-quarters looped internally. 512 thr, ~141 KB LDS, 1 block/CU.
__global__ __launch_bounds__(512) void se_kernel(
    const float* __restrict__ x,
    const float* __restrict__ se_key_w,   // 81*9
    const float* __restrict__ se_key_b,   // 81
    const float* __restrict__ se_att_w2,  // 9*81
    const float* __restrict__ se_att_b2,  // 9
    float* __restrict__ ws)
{
    __shared__ __align__(16) unsigned short xbh[CH];         // 82944 B fp16 x[b]
    __shared__ __align__(16) unsigned short kqs[128 * 200];  // 51200 B [col][k]
    __shared__ float wseL[DD * HW_];                         //  2916 B wse[tau][p]
    __shared__ float bseL[HW_];
    __shared__ float w2L[DD * 96];                           //  3456 B
    __shared__ float tseL[96];
    /* total ~141.2 KB */

    const int b = blockIdx.x;
    const int t = threadIdx.x;
    const float* xb = x + (size_t)b * CH;

    // ---- stage small weights ----
    for (int v = t; v < DD * HW_; v += 512) {
        int tau = v / 81, p = v - 81 * tau;
        wseL[tau * 81 + p] = se_key_w[p * 9 + tau];
    }
    if (t < HW_) bseL[t] = se_key_b[t];
    for (int v = t; v < DD * 96; v += 512) {
        int d = v / 96, row = v - 96 * d;
        w2L[v] = (row < 81) ? se_att_w2[d * 81 + row] : 0.f;
    }
    if (t < 96) tseL[t] = (t < 81) ? ws[WS_TSE + t] : 0.f;
    // zero-pad kqs rows 162..199 ONCE (never rewritten; must not be garbage
    // since fp16 garbage could be Inf/NaN -> 0*Inf = NaN in MFMA)
    for (int v = t; v < 128 * 38; v += 512) {
        int k = v >> 7, jl = v & 127;
        kqs[jl * 200 + 162 + k] = 0;
    }
    // ---- stage x -> fp16 LDS (coalesced float4, batched for MLP) ----
    {
        const float4* x4 = (const float4*)xb;
        #pragma unroll 4
        for (int v = t; v < CH / 4; v += 512) {
            float4 q = x4[v];
            ushort4 s4;
            s4.x = f2h(q.x); s4.y = f2h(q.y); s4.z = f2h(q.z); s4.w = f2h(q.w);
            *(ushort4*)(&xbh[4 * v]) = s4;
        }
    }
    __syncthreads();

    const int wv = t >> 6;          // wave 0..7, owns 16 cols per quarter
    const int lane = t & 63;
    const int quad = lane >> 4;
    const int l15 = lane & 15;
    const unsigned short* w1f = (const unsigned short*)(ws + WS_W1F);
    float* attout = ws + WS_ATT + (size_t)b * 4608;

    #pragma unroll 1
    for (int q = 0; q < 4; ++q) {
        const int c0 = q * 128;
        if (q) __syncthreads();     // prev quarter's frag reads done

        // build q-rows (k < 81): pure LDS transpose copy
        for (int v = t; v < 128 * 81; v += 512) {
            int k = v >> 7, jl = v & 127;
            kqs[jl * 200 + k] = xbh[k * 512 + c0 + jl];
        }
        // build k-rows (81 <= k < 162): 9-tap spectral conv, all from LDS
        for (int v = t; v < 128 * 81; v += 512) {
            int kk = v >> 7, jl = v & 127;
            int e = kk * 512 + c0 + jl;
            int p = e % 81;
            float s = bseL[p];
            #pragma unroll
            for (int tau = 0; tau < 9; ++tau) {
                int flat = e + (tau - 4) * 81;
                if (flat >= 0 && flat < CH)
                    s = fmaf(h2f(xbh[flat]), wseL[tau * 81 + p], s);
            }
            kqs[jl * 200 + 81 + kk] = f2h(s);
        }
        __syncthreads();

        // MFMA: C[96 x 128] = W1f[96 x 192] * KQ[192 x 128]
        f32x4 acc[6];
        #pragma unroll
        for (int m = 0; m < 6; ++m) acc[m] = (f32x4){0.f, 0.f, 0.f, 0.f};

        #pragma unroll 1
        for (int pass = 0; pass < 6; ++pass) {
            half8 bfr = *(const half8*)&kqs[(wv * 16 + l15) * 200 + pass * 32 + quad * 8];
            #pragma unroll
            for (int m = 0; m < 6; ++m) {
                half8 afr = *(const half8*)&w1f[(m * 16 + l15) * 192 + pass * 32 + quad * 8];
                acc[m] = __builtin_amdgcn_mfma_f32_16x16x32_f16(afr, bfr, acc[m], 0, 0, 0);
            }
        }

        // epilogue: relu(C + tse) -> fold 9x81 -> softmax -> ws ATT
        float pd[9];
        #pragma unroll
        for (int d = 0; d < 9; ++d) pd[d] = 0.f;
        #pragma unroll
        for (int m = 0; m < 6; ++m) {
            #pragma unroll
            for (int reg = 0; reg < 4; ++reg) {
                int row = m * 16 + quad * 4 + reg;
                float z = fmaxf(acc[m][reg] + tseL[row], 0.f);
                #pragma unroll
                for (int d = 0; d < 9; ++d)
                    pd[d] = fmaf(w2L[d * 96 + row], z, pd[d]);
            }
        }
        #pragma unroll
        for (int d = 0; d < 9; ++d) {
            pd[d] += __shfl_xor(pd[d], 16, 64);
            pd[d] += __shfl_xor(pd[d], 32, 64);
        }
        if (quad == 0) {
            int j = c0 + wv * 16 + l15;
            float ad[9];
            #pragma unroll
            for (int d = 0; d < 9; ++d) ad[d] = pd[d] + se_att_b2[d];
            float mm = ad[0];
            #pragma unroll
            for (int d = 1; d < 9; ++d) mm = fmaxf(mm, ad[d]);
            float ls = 0.f;
            #pragma unroll
            for (int d = 0; d < 9; ++d) { ad[d] = __expf(ad[d] - mm); ls += ad[d]; }
            float inv = 1.f / ls;
            #pragma unroll
            for (int d = 0; d < 9; ++d) attout[d * 512 + j] = ad[d] * inv;
        }
    }
}

// ============== Kernel B: combine, block = (batch, 64-channel tile) =========
// Round-3 profile: 177us, VALUBusy 26%, HBM 5%, Occupancy 22% -> latency-
// bound at 2 blocks/CU with ~38 scalar LDS reads per output. Fix: fp16
// xs/vs planes (LDS 60.9->37 KB -> 4 blocks/CU) + thread=(channel,slot)
// mapping so conv/att weights live in registers (~21 LDS reads/output).
__global__ __launch_bounds__(256, 4) void combine_kernel(
    const float* __restrict__ x,
    const float* __restrict__ alpha,
    const float* __restrict__ sa_key_w,   // 512*9
    const float* __restrict__ se_key_w,   // 81*9
    const float* __restrict__ se_key_b,   // 81
    const float* __restrict__ se_val_w,   // 512*9
    const float* __restrict__ se_val_b,   // 512
    const float* __restrict__ ws,
    float* __restrict__ out)
{
    __shared__ __align__(16) unsigned short xsh[72 * 81];  // 11664 B fp16
    __shared__ __align__(16) unsigned short vsh[72 * 81];  // 11664 B fp16
    __shared__ float wvL[72 * 9];
    __shared__ float bvL[72];
    __shared__ float wkL[64 * 9];
    __shared__ float s2L[64];
    __shared__ float t2L[64];
    __shared__ float wseT[9 * 81];  // transposed [tau][p]
    __shared__ float bseL[81];
    __shared__ float attL[9 * 64];
    __shared__ float a2L[8 * 81];
    /* ~37.2 KB -> 4 blocks/CU */

    const int bid = blockIdx.x;
    const int b = bid >> 3;
    const int tile = bid & 7;
    const int c0 = tile * 64;
    const int t = threadIdx.x;
    // (c0-4)*81 = 324*(16*tile - 1) is divisible by 4 -> float4-clean halo
    const int f04 = ((c0 - 4) * 81) >> 2;

    // ---- stage x (fp16, guarded float4) + weights ----
    {
        const float4* x4 = (const float4*)(x + (size_t)b * CH);
        for (int v = t; v < 1458; v += 256) {
            int g4 = f04 + v;
            float4 q = (g4 >= 0 && g4 < CH / 4) ? x4[g4]
                                                : (float4){0.f, 0.f, 0.f, 0.f};
            ushort4 s4;
            s4.x = f2h(q.x); s4.y = f2h(q.y); s4.z = f2h(q.z); s4.w = f2h(q.w);
            *(ushort4*)(&xsh[4 * v]) = s4;
        }
    }
    for (int idx = t; idx < 648; idx += 256) {
        int cc = c0 - 4 + idx / 9;
        wvL[idx] = (cc >= 0 && cc < 512) ? se_val_w[cc * 9 + idx % 9] : 0.f;
    }
    if (t < 72) {
        int cc = c0 - 4 + t;
        bvL[t] = (cc >= 0 && cc < 512) ? se_val_b[cc] : 0.f;
    }
    for (int idx = t; idx < 576; idx += 256) wkL[idx] = sa_key_w[c0 * 9 + idx];
    if (t < 64) { s2L[t] = ws[WS_S2 + c0 + t]; t2L[t] = ws[WS_T2 + c0 + t]; }
    for (int idx = t; idx < 729; idx += 256) {
        int p = idx / 9, tau = idx - 9 * p;
        wseT[tau * 81 + p] = se_key_w[idx];
    }
    if (t < 81) bseL[t] = se_key_b[t];
    for (int idx = t; idx < 576; idx += 256)
        attL[idx] = ws[WS_ATT + (size_t)b * 4608 + (idx >> 6) * 512 + c0 + (idx & 63)];
    for (int idx = t; idx < 648; idx += 256)
        a2L[idx] = ws[WS_A2 + (size_t)b * 5184 + tile * 648 + idx];
    __syncthreads();

    // ---- depthwise-v plane (3x3 conv + bias) -> fp16; zero OOB (= pad_v) ---
    for (int idx = t; idx < 5832; idx += 256) {
        int i = idx / 81, p = idx - 81 * i;
        int cc = c0 - 4 + i;
        float r = 0.f;
        if (cc >= 0 && cc < 512) {
            int y = p / 9, xx = p - 9 * (p / 9);
            float s = 0.f;
            #pragma unroll
            for (int ky = 0; ky < 3; ++ky) {
                int yy = y + ky - 1;
                if (yy < 0 || yy > 8) continue;
                #pragma unroll
                for (int kx = 0; kx < 3; ++kx) {
                    int xc = xx + kx - 1;
                    if (xc < 0 || xc > 8) continue;
                    s = fmaf(h2f(xsh[i * 81 + yy * 9 + xc]), wvL[i * 9 + ky * 3 + kx], s);
                }
            }
            r = s + bvL[i];
        }
        vsh[idx] = f2h(r);
    }
    __syncthreads();

    // ---- main: thread = (cl, slot); 21 pixels/slot; weights in registers ---
    const float av = alpha[0];
    const int cl = t >> 2, s = t & 3;
    float wk[9], attv[9];
    #pragma unroll
    for (int j = 0; j < 9; ++j) wk[j] = wkL[cl * 9 + j];
    #pragma unroll
    for (int d = 0; d < 9; ++d) attv[d] = attL[d * 64 + cl];
    const float s2 = s2L[cl], t2 = t2L[cl];
    const float* a2row = &a2L[(cl >> 3) * 81];
    float* outrow = out + (size_t)b * CH + (size_t)(c0 + cl) * 81;
    const int rowc = (cl + 4) * 81;   // conv/center row in xsh

    #pragma unroll 1
    for (int k = 0; k < 21; ++k) {
        int p = s + 4 * k;
        if (p < 81) {
            int y = p / 9, xx = p - 9 * y;
            // spatial key (3x3 dw conv -> bn -> relu), weights in regs
            float sk = 0.f;
            #pragma unroll
            for (int ky = 0; ky < 3; ++ky) {
                int yy = y + ky - 1;
                if (yy < 0 || yy > 8) continue;
                #pragma unroll
                for (int kx = 0; kx < 3; ++kx) {
                    int xc = xx + kx - 1;
                    if (xc < 0 || xc > 8) continue;
                    sk = fmaf(h2f(xsh[rowc + yy * 9 + xc]), wk[ky * 3 + kx], sk);
                }
            }
            float k1s = fmaxf(sk * s2 + t2, 0.f);
            // spectral attention combine (att weights in regs)
            float o1 = 0.f;
            #pragma unroll
            for (int d = 0; d < 9; ++d)
                o1 = fmaf(h2f(vsh[(cl + d) * 81 + p]), attv[d], o1);
            // spectral key value (k1) added to out1; wseT reads broadcast
            float k1se = bseL[p];
            #pragma unroll
            for (int tau = 0; tau < 9; ++tau)
                k1se = fmaf(h2f(xsh[(cl + tau) * 81 + p]), wseT[tau * 81 + p], k1se);
            float out2 = k1s + a2row[p] * h2f(xsh[rowc + p]);
            outrow[p] = av * (o1 + k1se) + (1.f - av) * out2;
        }
    }
}

extern "C" void kernel_launch(void* const* d_in, const int* in_sizes, int n_in,
                              void* d_out, int out_size, void* d_ws, size_t ws_size,
                              hipStream_t stream) {
    const float* x          = (const float*)d_in[0];
    const float* alpha      = (const float*)d_in[1];
    const float* sa_key_w   = (const float*)d_in[2];
    const float* sa_key_bn  = (const float*)d_in[3];
    const float* sa_att_w1  = (const float*)d_in[4];
    const float* sa_att_bn  = (const float*)d_in[5];
    const float* sa_att_w2  = (const float*)d_in[6];
    const float* sa_att_b2  = (const float*)d_in[7];
    const float* se_key_w   = (const float*)d_in[8];
    const float* se_key_b   = (const float*)d_in[9];
    const float* se_att_w1  = (const float*)d_in[10];
    const float* se_att_bn  = (const float*)d_in[11];
    const float* se_att_w2  = (const float*)d_in[12];
    const float* se_att_b2  = (const float*)d_in[13];
    const float* se_val_w   = (const float*)d_in[14];
    const float* se_val_b   = (const float*)d_in[15];
    float* ws = (float*)d_ws;
    float* outp = (float*)d_out;

    prep_kernel<<<(PREP_N + 255) / 256, 256, 0, stream>>>(
        se_att_w1, se_att_bn, sa_key_bn, sa_att_w1, sa_att_bn, ws);
    sa_kernel<<<BSZ * 4, 256, 0, stream>>>(
        x, sa_key_w, sa_att_w2, sa_att_b2, ws);
    se_kernel<<<BSZ, 512, 0, stream>>>(
        x, se_key_w, se_key_b, se_att_w2, se_att_b2, ws);
    combine_kernel<<<BSZ * 8, 256, 0, stream>>>(
        x, alpha, sa_key_w, se_key_w, se_key_b, se_val_w, se_val_b, ws, outp);
}

// Round 5
// 314.748 us; speedup vs baseline: 2.3508x; 1.1464x over previous
//
#include <hip/hip_runtime.h>
#include <hip/hip_fp16.h>

#define BSZ 256
#define CCH 512
#define HW_ 81
#define DD 9
#define CH 41472   /* CCH*HW_ */

/* ws layout (floats) */
#define WS_W1T   0        /* [162][81] folded+transposed se_att_w1 (legacy, unused) */
#define WS_TSE   13122    /* [81]  folded se_att bias */
#define WS_S2    13203    /* [512] sa_key bn scale */
#define WS_T2    13715    /* [512] sa_key bn bias */
#define WS_W1S   14227    /* [512][16] folded sa_att_w1 */
#define WS_T1    22419    /* [512] folded sa_att bias */
#define WS_A2    22932    /* [256][64][81] SaMCA attention */
#define WS_ATT   1350036  /* [256][9][512] SeMCA attention */
#define WS_W1F   2529684  /* [96][192] fp16 folded se_att_w1, zero-padded (ushorts) */
#define WS_TOTALP 22931   /* params region end */
#define PREP_N   41363    /* 22931 + 96*192/2 */

typedef _Float16 half8 __attribute__((ext_vector_type(8)));
typedef float f32x4 __attribute__((ext_vector_type(4)));

__device__ __forceinline__ float h2f(unsigned short u) {
    return __half2float(__ushort_as_half(u));
}
__device__ __forceinline__ unsigned short f2h(float f) {
    return __half_as_ushort(__float2half(f));
}

__global__ void prep_kernel(const float* __restrict__ se_att_w1,  // 81*162
                            const float* __restrict__ se_att_bn,  // 4*81
                            const float* __restrict__ sa_key_bn,  // 4*512
                            const float* __restrict__ sa_att_w1,  // 512*16
                            const float* __restrict__ sa_att_bn,  // 4*512
                            float* __restrict__ ws) {
    int idx = blockIdx.x * blockDim.x + threadIdx.x;
    if (idx < 13122) {
        int r = idx / 81, o = idx % 81;
        float g = se_att_bn[o], v = se_att_bn[243 + o];
        float s = g * rsqrtf(v + 1e-5f);
        ws[WS_W1T + idx] = se_att_w1[o * 162 + r] * s;
    } else if (idx < 13203) {
        int o = idx - 13122;
        float g = se_att_bn[o], b = se_att_bn[81 + o], m = se_att_bn[162 + o], v = se_att_bn[243 + o];
        float s = g * rsqrtf(v + 1e-5f);
        ws[WS_TSE + o] = b - m * s;
    } else if (idx < 13715) {
        int c = idx - 13203;
        float g = sa_key_bn[c], v = sa_key_bn[1536 + c];
        ws[WS_S2 + c] = g * rsqrtf(v + 1e-5f);
    } else if (idx < 14227) {
        int c = idx - 13715;
        float g = sa_key_bn[c], b = sa_key_bn[512 + c], m = sa_key_bn[1024 + c], v = sa_key_bn[1536 + c];
        float s = g * rsqrtf(v + 1e-5f);
        ws[WS_T2 + c] = b - m * s;
    } else if (idx < 22419) {
        int e = idx - 14227;
        int o = e >> 4;
        float g = sa_att_bn[o], v = sa_att_bn[1536 + o];
        float s = g * rsqrtf(v + 1e-5f);
        ws[WS_W1S + e] = sa_att_w1[e] * s;
    } else if (idx < WS_TOTALP) {
        int o = idx - 22419;
        float g = sa_att_bn[o], b = sa_att_bn[512 + o], m = sa_att_bn[1024 + o], v = sa_att_bn[1536 + o];
        float s = g * rsqrtf(v + 1e-5f);
        ws[WS_T1 + o] = b - m * s;
    } else if (idx < PREP_N) {
        // fp16 folded W1, padded [96][192] (two ushorts per float slot)
        int e2 = (idx - WS_TOTALP) * 2;
        unsigned int packed = 0;
        #pragma unroll
        for (int q = 0; q < 2; ++q) {
            int e = e2 + q;
            int row = e / 192, k = e - row * 192;
            unsigned short val = 0;
            if (row < 81 && k < 162) {
                float g = se_att_bn[row], v = se_att_bn[243 + row];
                float s = g * rsqrtf(v + 1e-5f);
                val = f2h(se_att_w1[row * 162 + k] * s);
            }
            packed |= ((unsigned int)val) << (16 * q);
        }
        ((unsigned int*)(ws + WS_W1F))[idx - WS_TOTALP] = packed;
    }
}

// ======== Kernel SA: SaMCA attention, grid = (batch x 4 ch-quarters) ========
// Round-5: 512 threads (was 256). LDS 74.9 KB -> 2 blocks/CU -> 16 waves/CU
// = 4 waves/SIMD (was 2) to hide LDS latency. Pass B remapped to 16 groups
// x 32 lanes x 3 pixel-slots; shuffle reduce stays within 32-lane halves.
__global__ __launch_bounds__(512, 4) void sa_kernel(
    const float* __restrict__ x,
    const float* __restrict__ sa_key_w,   // 512*9
    const float* __restrict__ sa_att_w2,  // 64*8
    const float* __restrict__ sa_att_b2,  // 64
    float* __restrict__ ws)
{
    __shared__ __align__(16) unsigned short xbh[128 * HW_]; // 20736 B fp16 x quarter
    __shared__ float kvf[128 * HW_];                        // 41472 B f32 kv plane
    __shared__ unsigned short wkbL[128 * DD];               //  2304 B
    __shared__ float s2L[128];
    __shared__ float t2L[128];
    __shared__ float w1sL[128 * 16];                        //  8192 B
    __shared__ float saw2L[128];
    __shared__ float b2L[16];
    __shared__ float t1L[128];
    /* total ~74.9 KB */

    const int bid = blockIdx.x;
    const int b = bid >> 2;
    const int qr = bid & 3;
    const int c0 = qr * 128;
    const int t = threadIdx.x;

    // ---- stage ----
    {
        const float4* x4 = (const float4*)(x + (size_t)b * CH + (size_t)c0 * 81);
        for (int v = t; v < 128 * 81 / 4; v += 512) {
            float4 q = x4[v];
            ushort4 s4;
            s4.x = f2h(q.x); s4.y = f2h(q.y); s4.z = f2h(q.z); s4.w = f2h(q.w);
            *(ushort4*)(&xbh[4 * v]) = s4;
        }
        for (int v = t; v < 128 * DD; v += 512) wkbL[v] = f2h(sa_key_w[c0 * 9 + v]);
        if (t < 128) {
            s2L[t] = ws[WS_S2 + c0 + t];
            t2L[t] = ws[WS_T2 + c0 + t];
            saw2L[t] = sa_att_w2[c0 + t];
            t1L[t] = ws[WS_T1 + c0 + t];
        }
        for (int v = t; v < 128 * 16; v += 512) w1sL[v] = ws[WS_W1S + c0 * 16 + v];
        if (t < 16) b2L[t] = sa_att_b2[qr * 16 + t];
    }
    __syncthreads();

    // ---- Pass A: kv = relu(bn(dwconv3x3(x))), f32 into LDS ----
    #pragma unroll 2
    for (int idx = t; idx < 128 * 81; idx += 512) {
        int c = idx / 81, p = idx - 81 * c;
        int y = p / 9, xx = p - 9 * y;
        float conv = 0.f;
        #pragma unroll
        for (int ky = 0; ky < 3; ++ky) {
            int yy = y + ky - 1;
            if (yy < 0 || yy > 8) continue;
            #pragma unroll
            for (int kx = 0; kx < 3; ++kx) {
                int xc = xx + kx - 1;
                if (xc < 0 || xc > 8) continue;
                conv = fmaf(h2f(xbh[c * 81 + yy * 9 + xc]),
                            h2f(wkbL[c * 9 + ky * 3 + kx]), conv);
            }
        }
        kvf[idx] = fmaxf(conv * s2L[c] + t2L[c], 0.f);
    }
    __syncthreads();

    // ---- Pass B: attention logits + softmax ----
    // 16 groups x 32 lanes; lane sub handles pixels p = sub + 32k, k<3.
    {
        const int g = t >> 5, sub = t & 31;
        const int cb = g * 8;                    // local channel base
        float z[8][3];
        #pragma unroll
        for (int o = 0; o < 8; ++o)
            #pragma unroll
            for (int k = 0; k < 3; ++k)
                z[o][k] = t1L[cb + o];

        #pragma unroll 1
        for (int j = 0; j < 8; ++j) {
            float wk[8], wx[8];
            #pragma unroll
            for (int o = 0; o < 8; ++o) {
                wk[o] = w1sL[(cb + o) * 16 + 2 * j];
                wx[o] = w1sL[(cb + o) * 16 + 2 * j + 1];
            }
            const int rowb = (cb + j) * 81;
            #pragma unroll
            for (int k = 0; k < 3; ++k) {
                int p = sub + 32 * k;
                if (p > 80) p = 80;              // clamp; masked at softmax
                float kv = kvf[rowb + p];
                float xv = h2f(xbh[rowb + p]);
                #pragma unroll
                for (int o = 0; o < 8; ++o) {
                    z[o][k] = fmaf(wk[o], kv, z[o][k]);
                    z[o][k] = fmaf(wx[o], xv, z[o][k]);
                }
            }
        }

        float a2v[3];
        const float b2g = b2L[g];
        #pragma unroll
        for (int k = 0; k < 3; ++k) {
            float s = b2g;
            #pragma unroll
            for (int o = 0; o < 8; ++o)
                s = fmaf(saw2L[cb + o], fmaxf(z[o][k], 0.f), s);
            int p = sub + 32 * k;
            a2v[k] = (p < 81) ? s : -1e30f;
        }

        // softmax over the 81 pixels (32 lanes x 3 slots, masked);
        // xor offsets 1..16 stay within this group's 32-lane half-wave.
        float m = a2v[0];
        #pragma unroll
        for (int k = 1; k < 3; ++k) m = fmaxf(m, a2v[k]);
        #pragma unroll
        for (int off = 1; off < 32; off <<= 1) m = fmaxf(m, __shfl_xor(m, off, 64));
        float ls = 0.f;
        float ev[3];
        #pragma unroll
        for (int k = 0; k < 3; ++k) { ev[k] = __expf(a2v[k] - m); ls += ev[k]; }
        #pragma unroll
        for (int off = 1; off < 32; off <<= 1) ls += __shfl_xor(ls, off, 64);
        float inv = 1.f / ls;

        float* a2out = ws + WS_A2 + (size_t)b * 5184 + (size_t)(qr * 16 + g) * 81;
        #pragma unroll
        for (int k = 0; k < 3; ++k) {
            int p = sub + 32 * k;
            if (p < 81) a2out[p] = ev[k] * inv;
        }
    }
}

// ======== Kernel SE: SeMCA attention via MFMA, grid = 256 (1 block/batch) ===
// Whole-batch x staged fp16 in LDS; KQ^T + spectral conv built from LDS.
// Round-5 build ILP fixes: interior fast-path (guards hoisted to one range
// check), incremental p (no %81 per element), strided kk-loops + unroll so
// independent ds_reads batch up (we only have 2 waves/SIMD here).
__global__ __launch_bounds__(512) void se_kernel(
    const float* __restrict__ x,
    const float* __restrict__ se_key_w,   // 81*9
    const float* __restrict__ se_key_b,   // 81
    const float* __restrict__ se_att_w2,  // 9*81
    const float* __restrict__ se_att_b2,  // 9
    float* __restrict__ ws)
{
    __shared__ __align__(16) unsigned short xbh[CH];         // 82944 B fp16 x[b]
    __shared__ __align__(16) unsigned short kqs[128 * 200];  // 51200 B [col][k]
    __shared__ float wseL[DD * HW_];                         //  2916 B wse[tau][p]
    __shared__ float bseL[HW_];
    __shared__ float w2L[DD * 96];                           //  3456 B
    __shared__ float tseL[96];
    /* total ~141.2 KB */

    const int b = blockIdx.x;
    const int t = threadIdx.x;
    const float* xb = x + (size_t)b * CH;

    // ---- stage small weights ----
    for (int v = t; v < DD * HW_; v += 512) {
        int tau = v / 81, p = v - 81 * tau;
        wseL[tau * 81 + p] = se_key_w[p * 9 + tau];
    }
    if (t < HW_) bseL[t] = se_key_b[t];
    for (int v = t; v < DD * 96; v += 512) {
        int d = v / 96, row = v - 96 * d;
        w2L[v] = (row < 81) ? se_att_w2[d * 81 + row] : 0.f;
    }
    if (t < 96) tseL[t] = (t < 81) ? ws[WS_TSE + t] : 0.f;
    // zero-pad kqs rows 162..199 ONCE (never rewritten; must not be garbage
    // since fp16 garbage could be Inf/NaN -> 0*Inf = NaN in MFMA)
    for (int v = t; v < 128 * 38; v += 512) {
        int k = v >> 7, jl = v & 127;
        kqs[jl * 200 + 162 + k] = 0;
    }
    // ---- stage x -> fp16 LDS (coalesced float4) ----
    {
        const float4* x4 = (const float4*)xb;
        #pragma unroll 4
        for (int v = t; v < CH / 4; v += 512) {
            float4 q = x4[v];
            ushort4 s4;
            s4.x = f2h(q.x); s4.y = f2h(q.y); s4.z = f2h(q.z); s4.w = f2h(q.w);
            *(ushort4*)(&xbh[4 * v]) = s4;
        }
    }
    __syncthreads();

    const int wv = t >> 6;          // wave 0..7, owns 16 cols per quarter
    const int lane = t & 63;
    const int quad = lane >> 4;
    const int l15 = lane & 15;
    const unsigned short* w1f = (const unsigned short*)(ws + WS_W1F);
    float* attout = ws + WS_ATT + (size_t)b * 4608;

    #pragma unroll 1
    for (int q = 0; q < 4; ++q) {
        const int c0 = q * 128;
        if (q) __syncthreads();     // prev quarter's frag reads done

        // build q-rows (k < 81): pure LDS transpose copy
        {
            int k = t >> 7;
            const int jl = t & 127;
            #pragma unroll 2
            for (; k < 81; k += 4)
                kqs[jl * 200 + k] = xbh[k * 512 + c0 + jl];
        }
        // build k-rows (81 <= k < 162): 9-tap spectral conv, all from LDS.
        // Interior fast path: guards live only at flat-array edges.
        {
            int kk = t >> 7;
            const int jl = t & 127;
            int e = kk * 512 + c0 + jl;
            int p = e % 81;                      // once; then incremental
            #pragma unroll 2
            for (; kk < 81; kk += 4) {
                float s = bseL[p];
                if (e >= 324 && e < CH - 324) {
                    #pragma unroll
                    for (int tau = 0; tau < 9; ++tau)
                        s = fmaf(h2f(xbh[e - 324 + 81 * tau]), wseL[tau * 81 + p], s);
                } else {
                    #pragma unroll
                    for (int tau = 0; tau < 9; ++tau) {
                        int flat = e + (tau - 4) * 81;
                        if (flat >= 0 && flat < CH)
                            s = fmaf(h2f(xbh[flat]), wseL[tau * 81 + p], s);
                    }
                }
                kqs[jl * 200 + 81 + kk] = f2h(s);
                e += 2048;
                p += 23; if (p >= 81) p -= 81;   // 2048 % 81 == 23
            }
        }
        __syncthreads();

        // MFMA: C[96 x 128] = W1f[96 x 192] * KQ[192 x 128]
        f32x4 acc[6];
        #pragma unroll
        for (int m = 0; m < 6; ++m) acc[m] = (f32x4){0.f, 0.f, 0.f, 0.f};

        #pragma unroll 1
        for (int pass = 0; pass < 6; ++pass) {
            half8 bfr = *(const half8*)&kqs[(wv * 16 + l15) * 200 + pass * 32 + quad * 8];
            #pragma unroll
            for (int m = 0; m < 6; ++m) {
                half8 afr = *(const half8*)&w1f[(m * 16 + l15) * 192 + pass * 32 + quad * 8];
                acc[m] = __builtin_amdgcn_mfma_f32_16x16x32_f16(afr, bfr, acc[m], 0, 0, 0);
            }
        }

        // epilogue: relu(C + tse) -> fold 9x81 -> softmax -> ws ATT
        float pd[9];
        #pragma unroll
        for (int d = 0; d < 9; ++d) pd[d] = 0.f;
        #pragma unroll
        for (int m = 0; m < 6; ++m) {
            #pragma unroll
            for (int reg = 0; reg < 4; ++reg) {
                int row = m * 16 + quad * 4 + reg;
                float z = fmaxf(acc[m][reg] + tseL[row], 0.f);
                #pragma unroll
                for (int d = 0; d < 9; ++d)
                    pd[d] = fmaf(w2L[d * 96 + row], z, pd[d]);
            }
        }
        #pragma unroll
        for (int d = 0; d < 9; ++d) {
            pd[d] += __shfl_xor(pd[d], 16, 64);
            pd[d] += __shfl_xor(pd[d], 32, 64);
        }
        if (quad == 0) {
            int j = c0 + wv * 16 + l15;
            float ad[9];
            #pragma unroll
            for (int d = 0; d < 9; ++d) ad[d] = pd[d] + se_att_b2[d];
            float mm = ad[0];
            #pragma unroll
            for (int d = 1; d < 9; ++d) mm = fmaxf(mm, ad[d]);
            float ls = 0.f;
            #pragma unroll
            for (int d = 0; d < 9; ++d) { ad[d] = __expf(ad[d] - mm); ls += ad[d]; }
            float inv = 1.f / ls;
            #pragma unroll
            for (int d = 0; d < 9; ++d) attout[d * 512 + j] = ad[d] * inv;
        }
    }
}

// ============== Kernel B: combine, block = (batch, 64-channel tile) =========
// fp16 xs/vs planes; 37 KB LDS -> 4 blocks/CU; weights in registers.
__global__ __launch_bounds__(256, 4) void combine_kernel(
    const float* __restrict__ x,
    const float* __restrict__ alpha,
    const float* __restrict__ sa_key_w,   // 512*9
    const float* __restrict__ se_key_w,   // 81*9
    const float* __restrict__ se_key_b,   // 81
    const float* __restrict__ se_val_w,   // 512*9
    const float* __restrict__ se_val_b,   // 512
    const float* __restrict__ ws,
    float* __restrict__ out)
{
    __shared__ __align__(16) unsigned short xsh[72 * 81];  // 11664 B fp16
    __shared__ __align__(16) unsigned short vsh[72 * 81];  // 11664 B fp16
    __shared__ float wvL[72 * 9];
    __shared__ float bvL[72];
    __shared__ float wkL[64 * 9];
    __shared__ float s2L[64];
    __shared__ float t2L[64];
    __shared__ float wseT[9 * 81];  // transposed [tau][p]
    __shared__ float bseL[81];
    __shared__ float attL[9 * 64];
    __shared__ float a2L[8 * 81];
    /* ~37.2 KB -> 4 blocks/CU */

    const int bid = blockIdx.x;
    const int b = bid >> 3;
    const int tile = bid & 7;
    const int c0 = tile * 64;
    const int t = threadIdx.x;
    // (c0-4)*81 = 324*(16*tile - 1) is divisible by 4 -> float4-clean halo
    const int f04 = ((c0 - 4) * 81) >> 2;

    // ---- stage x (fp16, guarded float4) + weights ----
    {
        const float4* x4 = (const float4*)(x + (size_t)b * CH);
        for (int v = t; v < 1458; v += 256) {
            int g4 = f04 + v;
            float4 q = (g4 >= 0 && g4 < CH / 4) ? x4[g4]
                                                : (float4){0.f, 0.f, 0.f, 0.f};
            ushort4 s4;
            s4.x = f2h(q.x); s4.y = f2h(q.y); s4.z = f2h(q.z); s4.w = f2h(q.w);
            *(ushort4*)(&xsh[4 * v]) = s4;
        }
    }
    for (int idx = t; idx < 648; idx += 256) {
        int cc = c0 - 4 + idx / 9;
        wvL[idx] = (cc >= 0 && cc < 512) ? se_val_w[cc * 9 + idx % 9] : 0.f;
    }
    if (t < 72) {
        int cc = c0 - 4 + t;
        bvL[t] = (cc >= 0 && cc < 512) ? se_val_b[cc] : 0.f;
    }
    for (int idx = t; idx < 576; idx += 256) wkL[idx] = sa_key_w[c0 * 9 + idx];
    if (t < 64) { s2L[t] = ws[WS_S2 + c0 + t]; t2L[t] = ws[WS_T2 + c0 + t]; }
    for (int idx = t; idx < 729; idx += 256) {
        int p = idx / 9, tau = idx - 9 * p;
        wseT[tau * 81 + p] = se_key_w[idx];
    }
    if (t < 81) bseL[t] = se_key_b[t];
    for (int idx = t; idx < 576; idx += 256)
        attL[idx] = ws[WS_ATT + (size_t)b * 4608 + (idx >> 6) * 512 + c0 + (idx & 63)];
    for (int idx = t; idx < 648; idx += 256)
        a2L[idx] = ws[WS_A2 + (size_t)b * 5184 + tile * 648 + idx];
    __syncthreads();

    // ---- depthwise-v plane (3x3 conv + bias) -> fp16; zero OOB (= pad_v) ---
    for (int idx = t; idx < 5832; idx += 256) {
        int i = idx / 81, p = idx - 81 * i;
        int cc = c0 - 4 + i;
        float r = 0.f;
        if (cc >= 0 && cc < 512) {
            int y = p / 9, xx = p - 9 * (p / 9);
            float s = 0.f;
            #pragma unroll
            for (int ky = 0; ky < 3; ++ky) {
                int yy = y + ky - 1;
                if (yy < 0 || yy > 8) continue;
                #pragma unroll
                for (int kx = 0; kx < 3; ++kx) {
                    int xc = xx + kx - 1;
                    if (xc < 0 || xc > 8) continue;
                    s = fmaf(h2f(xsh[i * 81 + yy * 9 + xc]), wvL[i * 9 + ky * 3 + kx], s);
                }
            }
            r = s + bvL[i];
        }
        vsh[idx] = f2h(r);
    }
    __syncthreads();

    // ---- main: thread = (cl, slot); 21 pixels/slot; weights in registers ---
    const float av = alpha[0];
    const int cl = t >> 2, s = t & 3;
    float wk[9], attv[9];
    #pragma unroll
    for (int j = 0; j < 9; ++j) wk[j] = wkL[cl * 9 + j];
    #pragma unroll
    for (int d = 0; d < 9; ++d) attv[d] = attL[d * 64 + cl];
    const float s2 = s2L[cl], t2 = t2L[cl];
    const float* a2row = &a2L[(cl >> 3) * 81];
    float* outrow = out + (size_t)b * CH + (size_t)(c0 + cl) * 81;
    const int rowc = (cl + 4) * 81;   // conv/center row in xsh

    #pragma unroll 1
    for (int k = 0; k < 21; ++k) {
        int p = s + 4 * k;
        if (p < 81) {
            int y = p / 9, xx = p - 9 * y;
            // spatial key (3x3 dw conv -> bn -> relu), weights in regs
            float sk = 0.f;
            #pragma unroll
            for (int ky = 0; ky < 3; ++ky) {
                int yy = y + ky - 1;
                if (yy < 0 || yy > 8) continue;
                #pragma unroll
                for (int kx = 0; kx < 3; ++kx) {
                    int xc = xx + kx - 1;
                    if (xc < 0 || xc > 8) continue;
                    sk = fmaf(h2f(xsh[rowc + yy * 9 + xc]), wk[ky * 3 + kx], sk);
                }
            }
            float k1s = fmaxf(sk * s2 + t2, 0.f);
            // spectral attention combine (att weights in regs)
            float o1 = 0.f;
            #pragma unroll
            for (int d = 0; d < 9; ++d)
                o1 = fmaf(h2f(vsh[(cl + d) * 81 + p]), attv[d], o1);
            // spectral key value (k1) added to out1; wseT reads broadcast
            float k1se = bseL[p];
            #pragma unroll
            for (int tau = 0; tau < 9; ++tau)
                k1se = fmaf(h2f(xsh[(cl + tau) * 81 + p]), wseT[tau * 81 + p], k1se);
            float out2 = k1s + a2row[p] * h2f(xsh[rowc + p]);
            outrow[p] = av * (o1 + k1se) + (1.f - av) * out2;
        }
    }
}

extern "C" void kernel_launch(void* const* d_in, const int* in_sizes, int n_in,
                              void* d_out, int out_size, void* d_ws, size_t ws_size,
                              hipStream_t stream) {
    const float* x          = (const float*)d_in[0];
    const float* alpha      = (const float*)d_in[1];
    const float* sa_key_w   = (const float*)d_in[2];
    const float* sa_key_bn  = (const float*)d_in[3];
    const float* sa_att_w1  = (const float*)d_in[4];
    const float* sa_att_bn  = (const float*)d_in[5];
    const float* sa_att_w2  = (const float*)d_in[6];
    const float* sa_att_b2  = (const float*)d_in[7];
    const float* se_key_w   = (const float*)d_in[8];
    const float* se_key_b   = (const float*)d_in[9];
    const float* se_att_w1  = (const float*)d_in[10];
    const float* se_att_bn  = (const float*)d_in[11];
    const float* se_att_w2  = (const float*)d_in[12];
    const float* se_att_b2  = (const float*)d_in[13];
    const float* se_val_w   = (const float*)d_in[14];
    const float* se_val_b   = (const float*)d_in[15];
    float* ws = (float*)d_ws;
    float* outp = (float*)d_out;

    prep_kernel<<<(PREP_N + 255) / 256, 256, 0, stream>>>(
        se_att_w1, se_att_bn, sa_key_bn, sa_att_w1, sa_att_bn, ws);
    sa_kernel<<<BSZ * 4, 512, 0, stream>>>(
        x, sa_key_w, sa_att_w2, sa_att_b2, ws);
    se_kernel<<<BSZ, 512, 0, stream>>>(
        x, se_key_w, se_key_b, se_att_w2, se_att_b2, ws);
    combine_kernel<<<BSZ * 8, 256, 0, stream>>>(
        x, alpha, sa_key_w, se_key_w, se_key_b, se_val_w, se_val_b, ws, outp);
}

// Round 7
// 291.849 us; speedup vs baseline: 2.5353x; 1.0785x over previous
//
#include <hip/hip_runtime.h>
#include <hip/hip_fp16.h>

#define BSZ 256
#define CCH 512
#define HW_ 81
#define DD 9
#define CH 41472   /* CCH*HW_ */

/* ws layout (floats) */
#define WS_W1T   0        /* [162][81] folded+transposed se_att_w1 (legacy, unused) */
#define WS_TSE   13122    /* [81]  folded se_att bias */
#define WS_S2    13203    /* [512] sa_key bn scale */
#define WS_T2    13715    /* [512] sa_key bn bias */
#define WS_W1S   14227    /* [512][16] folded sa_att_w1 */
#define WS_T1    22419    /* [512] folded sa_att bias */
#define WS_A2    22932    /* [256][64][81] SaMCA attention */
#define WS_ATT   1350036  /* [256][9][512] SeMCA attention */
#define WS_W1F   2529684  /* [96][192] fp16 folded se_att_w1, zero-padded (ushorts) */
#define WS_TOTALP 22931   /* params region end */
#define PREP_N   41363    /* 22931 + 96*192/2 */

typedef _Float16 half8 __attribute__((ext_vector_type(8)));
typedef float f32x4 __attribute__((ext_vector_type(4)));

__device__ __forceinline__ float h2f(unsigned short u) {
    return __half2float(__ushort_as_half(u));
}
__device__ __forceinline__ unsigned short f2h(float f) {
    return __half_as_ushort(__float2half(f));
}

__global__ void prep_kernel(const float* __restrict__ se_att_w1,  // 81*162
                            const float* __restrict__ se_att_bn,  // 4*81
                            const float* __restrict__ sa_key_bn,  // 4*512
                            const float* __restrict__ sa_att_w1,  // 512*16
                            const float* __restrict__ sa_att_bn,  // 4*512
                            float* __restrict__ ws) {
    int idx = blockIdx.x * blockDim.x + threadIdx.x;
    if (idx < 13122) {
        int r = idx / 81, o = idx % 81;
        float g = se_att_bn[o], v = se_att_bn[243 + o];
        float s = g * rsqrtf(v + 1e-5f);
        ws[WS_W1T + idx] = se_att_w1[o * 162 + r] * s;
    } else if (idx < 13203) {
        int o = idx - 13122;
        float g = se_att_bn[o], b = se_att_bn[81 + o], m = se_att_bn[162 + o], v = se_att_bn[243 + o];
        float s = g * rsqrtf(v + 1e-5f);
        ws[WS_TSE + o] = b - m * s;
    } else if (idx < 13715) {
        int c = idx - 13203;
        float g = sa_key_bn[c], v = sa_key_bn[1536 + c];
        ws[WS_S2 + c] = g * rsqrtf(v + 1e-5f);
    } else if (idx < 14227) {
        int c = idx - 13715;
        float g = sa_key_bn[c], b = sa_key_bn[512 + c], m = sa_key_bn[1024 + c], v = sa_key_bn[1536 + c];
        float s = g * rsqrtf(v + 1e-5f);
        ws[WS_T2 + c] = b - m * s;
    } else if (idx < 22419) {
        int e = idx - 14227;
        int o = e >> 4;
        float g = sa_att_bn[o], v = sa_att_bn[1536 + o];
        float s = g * rsqrtf(v + 1e-5f);
        ws[WS_W1S + e] = sa_att_w1[e] * s;
    } else if (idx < WS_TOTALP) {
        int o = idx - 22419;
        float g = sa_att_bn[o], b = sa_att_bn[512 + o], m = sa_att_bn[1024 + o], v = sa_att_bn[1536 + o];
        float s = g * rsqrtf(v + 1e-5f);
        ws[WS_T1 + o] = b - m * s;
    } else if (idx < PREP_N) {
        // fp16 folded W1, padded [96][192] (two ushorts per float slot)
        int e2 = (idx - WS_TOTALP) * 2;
        unsigned int packed = 0;
        #pragma unroll
        for (int q = 0; q < 2; ++q) {
            int e = e2 + q;
            int row = e / 192, k = e - row * 192;
            unsigned short val = 0;
            if (row < 81 && k < 162) {
                float g = se_att_bn[row], v = se_att_bn[243 + row];
                float s = g * rsqrtf(v + 1e-5f);
                val = f2h(se_att_w1[row * 162 + k] * s);
            }
            packed |= ((unsigned int)val) << (16 * q);
        }
        ((unsigned int*)(ws + WS_W1F))[idx - WS_TOTALP] = packed;
    }
}

// ======== Kernel SA: SaMCA attention, grid = (batch x 4 ch-quarters) ========
// 512 threads; 2 blocks/CU -> 4 waves/SIMD. (round-5 form, unchanged)
__global__ __launch_bounds__(512, 4) void sa_kernel(
    const float* __restrict__ x,
    const float* __restrict__ sa_key_w,   // 512*9
    const float* __restrict__ sa_att_w2,  // 64*8
    const float* __restrict__ sa_att_b2,  // 64
    float* __restrict__ ws)
{
    __shared__ __align__(16) unsigned short xbh[128 * HW_]; // 20736 B fp16 x quarter
    __shared__ float kvf[128 * HW_];                        // 41472 B f32 kv plane
    __shared__ unsigned short wkbL[128 * DD];               //  2304 B
    __shared__ float s2L[128];
    __shared__ float t2L[128];
    __shared__ float w1sL[128 * 16];                        //  8192 B
    __shared__ float saw2L[128];
    __shared__ float b2L[16];
    __shared__ float t1L[128];
    /* total ~74.9 KB */

    const int bid = blockIdx.x;
    const int b = bid >> 2;
    const int qr = bid & 3;
    const int c0 = qr * 128;
    const int t = threadIdx.x;

    // ---- stage ----
    {
        const float4* x4 = (const float4*)(x + (size_t)b * CH + (size_t)c0 * 81);
        for (int v = t; v < 128 * 81 / 4; v += 512) {
            float4 q = x4[v];
            ushort4 s4;
            s4.x = f2h(q.x); s4.y = f2h(q.y); s4.z = f2h(q.z); s4.w = f2h(q.w);
            *(ushort4*)(&xbh[4 * v]) = s4;
        }
        for (int v = t; v < 128 * DD; v += 512) wkbL[v] = f2h(sa_key_w[c0 * 9 + v]);
        if (t < 128) {
            s2L[t] = ws[WS_S2 + c0 + t];
            t2L[t] = ws[WS_T2 + c0 + t];
            saw2L[t] = sa_att_w2[c0 + t];
            t1L[t] = ws[WS_T1 + c0 + t];
        }
        for (int v = t; v < 128 * 16; v += 512) w1sL[v] = ws[WS_W1S + c0 * 16 + v];
        if (t < 16) b2L[t] = sa_att_b2[qr * 16 + t];
    }
    __syncthreads();

    // ---- Pass A: kv = relu(bn(dwconv3x3(x))), f32 into LDS ----
    #pragma unroll 2
    for (int idx = t; idx < 128 * 81; idx += 512) {
        int c = idx / 81, p = idx - 81 * c;
        int y = p / 9, xx = p - 9 * y;
        float conv = 0.f;
        #pragma unroll
        for (int ky = 0; ky < 3; ++ky) {
            int yy = y + ky - 1;
            if (yy < 0 || yy > 8) continue;
            #pragma unroll
            for (int kx = 0; kx < 3; ++kx) {
                int xc = xx + kx - 1;
                if (xc < 0 || xc > 8) continue;
                conv = fmaf(h2f(xbh[c * 81 + yy * 9 + xc]),
                            h2f(wkbL[c * 9 + ky * 3 + kx]), conv);
            }
        }
        kvf[idx] = fmaxf(conv * s2L[c] + t2L[c], 0.f);
    }
    __syncthreads();

    // ---- Pass B: attention logits + softmax ----
    // 16 groups x 32 lanes; lane sub handles pixels p = sub + 32k, k<3.
    {
        const int g = t >> 5, sub = t & 31;
        const int cb = g * 8;                    // local channel base
        float z[8][3];
        #pragma unroll
        for (int o = 0; o < 8; ++o)
            #pragma unroll
            for (int k = 0; k < 3; ++k)
                z[o][k] = t1L[cb + o];

        #pragma unroll 1
        for (int j = 0; j < 8; ++j) {
            float wk[8], wx[8];
            #pragma unroll
            for (int o = 0; o < 8; ++o) {
                wk[o] = w1sL[(cb + o) * 16 + 2 * j];
                wx[o] = w1sL[(cb + o) * 16 + 2 * j + 1];
            }
            const int rowb = (cb + j) * 81;
            #pragma unroll
            for (int k = 0; k < 3; ++k) {
                int p = sub + 32 * k;
                if (p > 80) p = 80;              // clamp; masked at softmax
                float kv = kvf[rowb + p];
                float xv = h2f(xbh[rowb + p]);
                #pragma unroll
                for (int o = 0; o < 8; ++o) {
                    z[o][k] = fmaf(wk[o], kv, z[o][k]);
                    z[o][k] = fmaf(wx[o], xv, z[o][k]);
                }
            }
        }

        float a2v[3];
        const float b2g = b2L[g];
        #pragma unroll
        for (int k = 0; k < 3; ++k) {
            float s = b2g;
            #pragma unroll
            for (int o = 0; o < 8; ++o)
                s = fmaf(saw2L[cb + o], fmaxf(z[o][k], 0.f), s);
            int p = sub + 32 * k;
            a2v[k] = (p < 81) ? s : -1e30f;
        }

        // softmax over the 81 pixels (32 lanes x 3 slots, masked);
        // xor offsets 1..16 stay within this group's 32-lane half-wave.
        float m = a2v[0];
        #pragma unroll
        for (int k = 1; k < 3; ++k) m = fmaxf(m, a2v[k]);
        #pragma unroll
        for (int off = 1; off < 32; off <<= 1) m = fmaxf(m, __shfl_xor(m, off, 64));
        float ls = 0.f;
        float ev[3];
        #pragma unroll
        for (int k = 0; k < 3; ++k) { ev[k] = __expf(a2v[k] - m); ls += ev[k]; }
        #pragma unroll
        for (int off = 1; off < 32; off <<= 1) ls += __shfl_xor(ls, off, 64);
        float inv = 1.f / ls;

        float* a2out = ws + WS_A2 + (size_t)b * 5184 + (size_t)(qr * 16 + g) * 81;
        #pragma unroll
        for (int k = 0; k < 3; ++k) {
            int p = sub + 32 * k;
            if (p < 81) a2out[p] = ev[k] * inv;
        }
    }
}

// ======== Kernel SE: SeMCA attention via MFMA, grid = 256 (1 block/batch) ===
// (round-5 form, unchanged)
__global__ __launch_bounds__(512) void se_kernel(
    const float* __restrict__ x,
    const float* __restrict__ se_key_w,   // 81*9
    const float* __restrict__ se_key_b,   // 81
    const float* __restrict__ se_att_w2,  // 9*81
    const float* __restrict__ se_att_b2,  // 9
    float* __restrict__ ws)
{
    __shared__ __align__(16) unsigned short xbh[CH];         // 82944 B fp16 x[b]
    __shared__ __align__(16) unsigned short kqs[128 * 200];  // 51200 B [col][k]
    __shared__ float wseL[DD * HW_];                         //  2916 B wse[tau][p]
    __shared__ float bseL[HW_];
    __shared__ float w2L[DD * 96];                           //  3456 B
    __shared__ float tseL[96];
    /* total ~141.2 KB */

    const int b = blockIdx.x;
    const int t = threadIdx.x;
    const float* xb = x + (size_t)b * CH;

    // ---- stage small weights ----
    for (int v = t; v < DD * HW_; v += 512) {
        int tau = v / 81, p = v - 81 * tau;
        wseL[tau * 81 + p] = se_key_w[p * 9 + tau];
    }
    if (t < HW_) bseL[t] = se_key_b[t];
    for (int v = t; v < DD * 96; v += 512) {
        int d = v / 96, row = v - 96 * d;
        w2L[v] = (row < 81) ? se_att_w2[d * 81 + row] : 0.f;
    }
    if (t < 96) tseL[t] = (t < 81) ? ws[WS_TSE + t] : 0.f;
    // zero-pad kqs rows 162..199 ONCE
    for (int v = t; v < 128 * 38; v += 512) {
        int k = v >> 7, jl = v & 127;
        kqs[jl * 200 + 162 + k] = 0;
    }
    // ---- stage x -> fp16 LDS (coalesced float4) ----
    {
        const float4* x4 = (const float4*)xb;
        #pragma unroll 4
        for (int v = t; v < CH / 4; v += 512) {
            float4 q = x4[v];
            ushort4 s4;
            s4.x = f2h(q.x); s4.y = f2h(q.y); s4.z = f2h(q.z); s4.w = f2h(q.w);
            *(ushort4*)(&xbh[4 * v]) = s4;
        }
    }
    __syncthreads();

    const int wv = t >> 6;          // wave 0..7, owns 16 cols per quarter
    const int lane = t & 63;
    const int quad = lane >> 4;
    const int l15 = lane & 15;
    const unsigned short* w1f = (const unsigned short*)(ws + WS_W1F);
    float* attout = ws + WS_ATT + (size_t)b * 4608;

    #pragma unroll 1
    for (int q = 0; q < 4; ++q) {
        const int c0 = q * 128;
        if (q) __syncthreads();     // prev quarter's frag reads done

        // build q-rows (k < 81): pure LDS transpose copy
        {
            int k = t >> 7;
            const int jl = t & 127;
            #pragma unroll 2
            for (; k < 81; k += 4)
                kqs[jl * 200 + k] = xbh[k * 512 + c0 + jl];
        }
        // build k-rows (81 <= k < 162): 9-tap spectral conv, all from LDS.
        {
            int kk = t >> 7;
            const int jl = t & 127;
            int e = kk * 512 + c0 + jl;
            int p = e % 81;                      // once; then incremental
            #pragma unroll 2
            for (; kk < 81; kk += 4) {
                float s = bseL[p];
                if (e >= 324 && e < CH - 324) {
                    #pragma unroll
                    for (int tau = 0; tau < 9; ++tau)
                        s = fmaf(h2f(xbh[e - 324 + 81 * tau]), wseL[tau * 81 + p], s);
                } else {
                    #pragma unroll
                    for (int tau = 0; tau < 9; ++tau) {
                        int flat = e + (tau - 4) * 81;
                        if (flat >= 0 && flat < CH)
                            s = fmaf(h2f(xbh[flat]), wseL[tau * 81 + p], s);
                    }
                }
                kqs[jl * 200 + 81 + kk] = f2h(s);
                e += 2048;
                p += 23; if (p >= 81) p -= 81;   // 2048 % 81 == 23
            }
        }
        __syncthreads();

        // MFMA: C[96 x 128] = W1f[96 x 192] * KQ[192 x 128]
        f32x4 acc[6];
        #pragma unroll
        for (int m = 0; m < 6; ++m) acc[m] = (f32x4){0.f, 0.f, 0.f, 0.f};

        #pragma unroll 1
        for (int pass = 0; pass < 6; ++pass) {
            half8 bfr = *(const half8*)&kqs[(wv * 16 + l15) * 200 + pass * 32 + quad * 8];
            #pragma unroll
            for (int m = 0; m < 6; ++m) {
                half8 afr = *(const half8*)&w1f[(m * 16 + l15) * 192 + pass * 32 + quad * 8];
                acc[m] = __builtin_amdgcn_mfma_f32_16x16x32_f16(afr, bfr, acc[m], 0, 0, 0);
            }
        }

        // epilogue: relu(C + tse) -> fold 9x81 -> softmax -> ws ATT
        float pd[9];
        #pragma unroll
        for (int d = 0; d < 9; ++d) pd[d] = 0.f;
        #pragma unroll
        for (int m = 0; m < 6; ++m) {
            #pragma unroll
            for (int reg = 0; reg < 4; ++reg) {
                int row = m * 16 + quad * 4 + reg;
                float z = fmaxf(acc[m][reg] + tseL[row], 0.f);
                #pragma unroll
                for (int d = 0; d < 9; ++d)
                    pd[d] = fmaf(w2L[d * 96 + row], z, pd[d]);
            }
        }
        #pragma unroll
        for (int d = 0; d < 9; ++d) {
            pd[d] += __shfl_xor(pd[d], 16, 64);
            pd[d] += __shfl_xor(pd[d], 32, 64);
        }
        if (quad == 0) {
            int j = c0 + wv * 16 + l15;
            float ad[9];
            #pragma unroll
            for (int d = 0; d < 9; ++d) ad[d] = pd[d] + se_att_b2[d];
            float mm = ad[0];
            #pragma unroll
            for (int d = 1; d < 9; ++d) mm = fmaxf(mm, ad[d]);
            float ls = 0.f;
            #pragma unroll
            for (int d = 0; d < 9; ++d) { ad[d] = __expf(ad[d] - mm); ls += ad[d]; }
            float inv = 1.f / ls;
            #pragma unroll
            for (int d = 0; d < 9; ++d) attout[d * 512 + j] = ad[d] * inv;
        }
    }
}

// ============== Kernel B: combine, block = (batch, 64-channel tile) =========
// Round-6 rewrite: row-vectorized. Unit = (channel, image-row): 9 outputs
// from contiguous vector row-loads. LDS planes padded [ch][9][12] so every
// row is 8B-aligned (ushort4/float4 loads). ~6 vector LDS reads/px vs 27
// scalar before. ~46 KB LDS -> 3 blocks/CU.
#define CS 108   /* channel stride in padded plane (9 rows * 12) */
#define RS 12    /* row stride */

__device__ __forceinline__ void ldrow_h(const unsigned short* base, float* r) {
    ushort4 a = *(const ushort4*)(base);
    ushort4 bq = *(const ushort4*)(base + 4);
    unsigned short c = base[8];
    r[0] = h2f(a.x); r[1] = h2f(a.y); r[2] = h2f(a.z); r[3] = h2f(a.w);
    r[4] = h2f(bq.x); r[5] = h2f(bq.y); r[6] = h2f(bq.z); r[7] = h2f(bq.w);
    r[8] = h2f(c);
}
__device__ __forceinline__ void ldrow_f(const float* base, float* r) {
    float4 a = *(const float4*)(base);
    float4 bq = *(const float4*)(base + 4);
    r[0] = a.x; r[1] = a.y; r[2] = a.z; r[3] = a.w;
    r[4] = bq.x; r[5] = bq.y; r[6] = bq.z; r[7] = bq.w;
    r[8] = base[8];
}
__device__ __forceinline__ void zrow(float* r) {
    #pragma unroll
    for (int xx = 0; xx < 9; ++xx) r[xx] = 0.f;
}

__global__ __launch_bounds__(256) void combine_kernel(
    const float* __restrict__ x,
    const float* __restrict__ alpha,
    const float* __restrict__ sa_key_w,   // 512*9
    const float* __restrict__ se_key_w,   // 81*9
    const float* __restrict__ se_key_b,   // 81
    const float* __restrict__ se_val_w,   // 512*9
    const float* __restrict__ se_val_b,   // 512
    const float* __restrict__ ws,
    float* __restrict__ out)
{
    __shared__ __align__(16) unsigned short xsh[72 * CS];  // 15552 B fp16 padded
    __shared__ __align__(16) unsigned short vsh[72 * CS];  // 15552 B fp16 padded
    __shared__ __align__(16) float wsePad[9 * CS];         //  3888 B [tau][y][12]
    __shared__ __align__(16) float bsePad[CS];             //   432 B [y][12]
    __shared__ __align__(16) float a2Pad[8 * CS];          //  3456 B [g][y][12]
    __shared__ float wvL[72 * 9];                          //  2592 B
    __shared__ float bvL[72];
    __shared__ float wkL[64 * 9];                          //  2304 B
    __shared__ float s2L[64];
    __shared__ float t2L[64];
    __shared__ float attL[9 * 64];                         //  2304 B
    /* ~45.9 KB -> 3 blocks/CU */

    const int bid = blockIdx.x;
    const int b = bid >> 3;
    const int tile = bid & 7;
    const int c0 = tile * 64;
    const int t = threadIdx.x;
    const int f0 = (c0 - 4) * 81;          // divisible by 4

    // ---- stage x into padded fp16 plane (guarded float4 reads) ----
    {
        const float* xg = x + (size_t)b * CH;
        for (int v4 = t; v4 < 1458; v4 += 256) {
            int lf = v4 * 4;
            int gf = f0 + lf;
            float4 q = (gf >= 0 && gf < CH) ? *(const float4*)(xg + gf)
                                            : (float4){0.f, 0.f, 0.f, 0.f};
            #pragma unroll
            for (int j = 0; j < 4; ++j) {
                int lfj = lf + j;
                int i = lfj / 81, p = lfj - 81 * i;
                int yy = p / 9, xx = p - 9 * yy;
                xsh[i * CS + yy * RS + xx] = f2h(((const float*)&q)[j]);
            }
        }
    }
    // ---- stage weights ----
    for (int idx = t; idx < 648; idx += 256) {
        int cc = c0 - 4 + idx / 9;
        wvL[idx] = (cc >= 0 && cc < 512) ? se_val_w[cc * 9 + idx % 9] : 0.f;
    }
    if (t < 72) {
        int cc = c0 - 4 + t;
        bvL[t] = (cc >= 0 && cc < 512) ? se_val_b[cc] : 0.f;
    }
    for (int idx = t; idx < 576; idx += 256) wkL[idx] = sa_key_w[c0 * 9 + idx];
    if (t < 64) { s2L[t] = ws[WS_S2 + c0 + t]; t2L[t] = ws[WS_T2 + c0 + t]; }
    for (int idx = t; idx < 972; idx += 256) {
        int tau = idx / CS, r = idx - CS * tau;
        int yy = r / RS, xx = r - RS * yy;
        if (xx < 9) wsePad[idx] = se_key_w[(yy * 9 + xx) * 9 + tau];
    }
    if (t < CS) {
        int yy = t / RS, xx = t - RS * yy;
        if (xx < 9) bsePad[t] = se_key_b[yy * 9 + xx];
    }
    for (int idx = t; idx < 864; idx += 256) {
        int g = idx / CS, r = idx - CS * g;
        int yy = r / RS, xx = r - RS * yy;
        if (xx < 9)
            a2Pad[idx] = ws[WS_A2 + (size_t)b * 5184 + (size_t)(tile * 8 + g) * 81 + yy * 9 + xx];
    }
    for (int idx = t; idx < 576; idx += 256)
        attL[idx] = ws[WS_ATT + (size_t)b * 4608 + (idx >> 6) * 512 + c0 + (idx & 63)];
    __syncthreads();

    // ---- v-plane: dwconv3x3 + bias, row-vectorized -> padded fp16 plane ----
    #pragma unroll 1
    for (int u = t; u < 648; u += 256) {
        int i = u / 9, yy = u - 9 * i;
        const int cb = i * CS;
        float q0[9], q1[9], q2[9];
        if (yy > 0) ldrow_h(&xsh[cb + (yy - 1) * RS], q0);
        else zrow(q0);
        ldrow_h(&xsh[cb + yy * RS], q1);
        if (yy < 8) ldrow_h(&xsh[cb + (yy + 1) * RS], q2);
        else zrow(q2);
        float wv[9];
        #pragma unroll
        for (int j = 0; j < 9; ++j) wv[j] = wvL[i * 9 + j];
        const float bv = bvL[i];
        float o[9];
        #pragma unroll
        for (int xx = 0; xx < 9; ++xx) {
            float s = bv;
            #pragma unroll
            for (int kx = 0; kx < 3; ++kx) {
                int xc = xx + kx - 1;
                if (xc >= 0 && xc <= 8) {
                    s = fmaf(q0[xc], wv[kx], s);
                    s = fmaf(q1[xc], wv[3 + kx], s);
                    s = fmaf(q2[xc], wv[6 + kx], s);
                }
            }
            o[xx] = s;     // OOB channels: wv=bv=0 and xsh=0 -> 0 (= pad_v)
        }
        const int vb = cb + yy * RS;
        ushort4 wA, wB;
        wA.x = f2h(o[0]); wA.y = f2h(o[1]); wA.z = f2h(o[2]); wA.w = f2h(o[3]);
        wB.x = f2h(o[4]); wB.y = f2h(o[5]); wB.z = f2h(o[6]); wB.w = f2h(o[7]);
        *(ushort4*)(&vsh[vb]) = wA;
        *(ushort4*)(&vsh[vb + 4]) = wB;
        vsh[vb + 8] = f2h(o[8]);
    }
    __syncthreads();

    // ---- main: unit = (cl, y) -> 9 outputs via row loads ----
    const float av = alpha[0];
    #pragma unroll 1
    for (int u = t; u < 576; u += 256) {
        int cl = u / 9, yy = u - 9 * cl;
        const int rb = yy * RS;
        float acc[9];
        ldrow_f(&bsePad[rb], acc);                 // k1se bias
        float r1[9];
        // k1se: 9 spectral taps (channels cl..cl+8 in halo = global c-4..c+4)
        #pragma unroll
        for (int tau = 0; tau < 9; ++tau) {
            float xr[9], wr[9];
            ldrow_h(&xsh[(cl + tau) * CS + rb], xr);
            ldrow_f(&wsePad[tau * CS + rb], wr);
            #pragma unroll
            for (int xx = 0; xx < 9; ++xx) acc[xx] = fmaf(xr[xx], wr[xx], acc[xx]);
            if (tau == 4) {
                #pragma unroll
                for (int xx = 0; xx < 9; ++xx) r1[xx] = xr[xx];  // center row
            }
        }
        // o1: 9 spectral-attention taps over v
        #pragma unroll
        for (int d = 0; d < 9; ++d) {
            float vr[9];
            ldrow_h(&vsh[(cl + d) * CS + rb], vr);
            const float ad = attL[d * 64 + cl];
            #pragma unroll
            for (int xx = 0; xx < 9; ++xx) acc[xx] = fmaf(vr[xx], ad, acc[xx]);
        }
        // spatial key conv rows (r1 reused as center)
        float r0[9], r2[9];
        if (yy > 0) ldrow_h(&xsh[(cl + 4) * CS + rb - RS], r0);
        else zrow(r0);
        if (yy < 8) ldrow_h(&xsh[(cl + 4) * CS + rb + RS], r2);
        else zrow(r2);
        float wkr[9];
        #pragma unroll
        for (int j = 0; j < 9; ++j) wkr[j] = wkL[cl * 9 + j];
        const float s2 = s2L[cl], t2v = t2L[cl];
        float a2r[9];
        ldrow_f(&a2Pad[(cl >> 3) * CS + rb], a2r);
        float* orow = out + (size_t)b * CH + (size_t)(c0 + cl) * 81 + yy * 9;
        #pragma unroll
        for (int xx = 0; xx < 9; ++xx) {
            float sk = 0.f;
            #pragma unroll
            for (int kx = 0; kx < 3; ++kx) {
                int xc = xx + kx - 1;
                if (xc >= 0 && xc <= 8) {
                    sk = fmaf(r0[xc], wkr[kx], sk);
                    sk = fmaf(r1[xc], wkr[3 + kx], sk);
                    sk = fmaf(r2[xc], wkr[6 + kx], sk);
                }
            }
            float k1s = fmaxf(sk * s2 + t2v, 0.f);
            float out2 = k1s + a2r[xx] * r1[xx];
            orow[xx] = av * acc[xx] + (1.f - av) * out2;
        }
    }
}

extern "C" void kernel_launch(void* const* d_in, const int* in_sizes, int n_in,
                              void* d_out, int out_size, void* d_ws, size_t ws_size,
                              hipStream_t stream) {
    const float* x          = (const float*)d_in[0];
    const float* alpha      = (const float*)d_in[1];
    const float* sa_key_w   = (const float*)d_in[2];
    const float* sa_key_bn  = (const float*)d_in[3];
    const float* sa_att_w1  = (const float*)d_in[4];
    const float* sa_att_bn  = (const float*)d_in[5];
    const float* sa_att_w2  = (const float*)d_in[6];
    const float* sa_att_b2  = (const float*)d_in[7];
    const float* se_key_w   = (const float*)d_in[8];
    const float* se_key_b   = (const float*)d_in[9];
    const float* se_att_w1  = (const float*)d_in[10];
    const float* se_att_bn  = (const float*)d_in[11];
    const float* se_att_w2  = (const float*)d_in[12];
    const float* se_att_b2  = (const float*)d_in[13];
    const float* se_val_w   = (const float*)d_in[14];
    const float* se_val_b   = (const float*)d_in[15];
    float* ws = (float*)d_ws;
    float* outp = (float*)d_out;

    prep_kernel<<<(PREP_N + 255) / 256, 256, 0, stream>>>(
        se_att_w1, se_att_bn, sa_key_bn, sa_att_w1, sa_att_bn, ws);
    sa_kernel<<<BSZ * 4, 512, 0, stream>>>(
        x, sa_key_w, sa_att_w2, sa_att_b2, ws);
    se_kernel<<<BSZ, 512, 0, stream>>>(
        x, se_key_w, se_key_b, se_att_w2, se_att_b2, ws);
    combine_kernel<<<BSZ * 8, 256, 0, stream>>>(
        x, alpha, sa_key_w, se_key_w, se_key_b, se_val_w, se_val_b, ws, outp);
}